// Round 2
// baseline (1682.899 us; speedup 1.0000x reference)
//
#include <hip/hip_runtime.h>
#include <math.h>

// Problem constants (from reference setup_inputs)
#define BB 128        // batch
#define NN 2000       // nodes
#define EE 20000      // edges
#define CC 16         // channels
#define FUNC_LO 200   // func nodes: [200, 1800)
#define FUNC_HI 1800
#define OUT_LO 1800   // output nodes: [1800, 2000)
#define OUTN 200
#define NFUNC 1600
#define NBLK 1600     // fused-kernel grid (1 block per func node)
#define EPSV 1e-5f
#define SS 40         // fixed slots per node per direction (Poisson(10): P(deg>40)~1e-15)
#define HP 129        // padded LDS stride

// ---------------- manual grid barrier ----------------
// Sense-reversal barrier on agent-scope atomics (same mechanism cg::grid_sync
// uses, but independent of hipLaunchCooperativeKernel, which failed under the
// harness's graph capture in round 1). Co-residency is by construction:
// __launch_bounds__(128,4) caps VGPR<=128 -> 8 blocks/CU; LDS 9.4KB*8=75KB<160KB;
// grid 1600 <= 8*256=2048. Bounded spin = no hang even if that breaks.
__device__ __forceinline__ void gsync(unsigned* cnt, unsigned* gen) {
    __syncthreads();
    if (threadIdx.x == 0) {
        unsigned g = __hip_atomic_load(gen, __ATOMIC_RELAXED, __HIP_MEMORY_SCOPE_AGENT);
        unsigned old = __hip_atomic_fetch_add(cnt, 1u, __ATOMIC_ACQ_REL, __HIP_MEMORY_SCOPE_AGENT);
        if (old == NBLK - 1u) {
            __hip_atomic_store(cnt, 0u, __ATOMIC_RELAXED, __HIP_MEMORY_SCOPE_AGENT);
            __hip_atomic_fetch_add(gen, 1u, __ATOMIC_ACQ_REL, __HIP_MEMORY_SCOPE_AGENT);
        } else {
            int spins = 0;
            while (__hip_atomic_load(gen, __ATOMIC_ACQUIRE, __HIP_MEMORY_SCOPE_AGENT) == g) {
                __builtin_amdgcn_s_sleep(2);
                if (++spins > (1 << 20)) break;   // safety valve vs deadlock
            }
        }
    }
    __syncthreads();
}

// ---------------- prep: slot assign + operand gather + transpose + outT zero ------
// In-slots: only func-dst edges get one (others are never read).
// Out-slots (func-src only), pre-compacted: func-dst edges fill [0,degF) from the
// front; out-dst edges fill from the back (SS-1 downward). Input-dst edges get
// nothing (dead). This removes the dstn load + liveness branch from Phase C.
__global__ void k_prep(const float* __restrict__ x, const int* __restrict__ ei,
                       const float* __restrict__ w1, const float* __restrict__ w3,
                       const float* __restrict__ b3,
                       int* __restrict__ degIn, int* __restrict__ degF,
                       int* __restrict__ degO, int* __restrict__ posIn,
                       float* __restrict__ xT, float* __restrict__ w1s,
                       float* __restrict__ w3s, float* __restrict__ b3s,
                       int* __restrict__ inoff, int* __restrict__ wout,
                       float* __restrict__ outT)
{
    int t = blockIdx.x * 256 + threadIdx.x;
    if (t < EE) {
        int s = ei[t], d = ei[EE + t];
        bool dFn = (d >= FUNC_LO && d < FUNC_HI);
        bool sFn = (s >= FUNC_LO && s < FUNC_HI);
        int pi = -1;
        if (dFn) {                                  // in-slot at dst
            int p = atomicAdd(&degIn[d], 1);
            pi = d * SS + p;
            posIn[t] = pi;
            const float4* w1v = (const float4*)w1 + (size_t)t * 4;
            float4* w1o = (float4*)w1s + (size_t)pi * 4;
            #pragma unroll
            for (int i = 0; i < 4; i++) w1o[i] = w1v[i];
            inoff[pi] = s * BB;                     // layer-0 input row = xT[src]
        }
        if (sFn) {                                  // out-slot at src (live only)
            int po = -1;
            if (dFn) {
                int q = atomicAdd(&degF[s], 1);
                po = s * SS + q;                    // front: func-dst
                wout[po] = pi * BB;                 // write row = dst's in-slot
            } else if (d >= OUT_LO) {
                int q = atomicAdd(&degO[s], 1);
                po = s * SS + (SS - 1 - q);         // back: out-dst
                wout[po] = (d - OUT_LO) * BB;       // outT row
            }
            if (po >= 0) {
                const float4* w3v = (const float4*)w3 + (size_t)t * 4;
                float4* w3o = (float4*)w3s + (size_t)po * 4;
                #pragma unroll
                for (int i = 0; i < 4; i++) w3o[i] = w3v[i];
                b3s[po] = b3[t];
            }
        }
    }
    if (t < OUTN * BB) outT[t] = 0.0f;
    if (t < NN * BB) {                 // transpose x (B,N) -> xT (N,B)
        int b = t / NN, n = t - b * NN;
        xT[n * BB + b] = x[t];
    }
}

// ---------------- batchnorm + elu over a per-thread register column ----------------
__device__ __forceinline__ void bn_elu(float (&t)[CC],
                                       const float* __restrict__ g,
                                       const float* __restrict__ be,
                                       float* tile, float* part_s, float* part_ss,
                                       float* sc, float* sh, int b) {
    #pragma unroll
    for (int c = 0; c < CC; c++) tile[c * HP + b] = t[c];
    __syncthreads();
    {
        int c = b & 15, grp = b >> 4;          // 16 channels x 8 groups of 16 b
        float s = 0.f, ss = 0.f;
        #pragma unroll
        for (int i = 0; i < 16; i++) {
            float v = tile[c * HP + grp * 16 + i];
            s += v; ss += v * v;
        }
        part_s[grp * 16 + c] = s;
        part_ss[grp * 16 + c] = ss;
    }
    __syncthreads();
    if (b < CC) {
        float S = 0.f, SSm = 0.f;
        #pragma unroll
        for (int g8 = 0; g8 < 8; g8++) { S += part_s[g8 * 16 + b]; SSm += part_ss[g8 * 16 + b]; }
        float mean = S * (1.0f / BB);
        float var = SSm * (1.0f / BB) - mean * mean;
        float scale = rsqrtf(var + EPSV) * g[b];
        sc[b] = scale;
        sh[b] = be[b] - mean * scale;
    }
    __syncthreads();
    #pragma unroll
    for (int c = 0; c < CC; c++) {
        float u = t[c] * sc[c] + sh[c];
        t[c] = (u > 0.0f) ? u : (__expf(u) - 1.0f);
    }
}

// ---------------- fused kernel: fill + 4 layers + finalize ----------------
struct FusedArgs {
    const float* xT; float* xeA; float* xeB;
    const float* w1s; const float* w2; const float* w3s; const float* b3s;
    const int* inoff; const int* wout;
    const int* degIn; const int* degF; const int* degO;
    const float* g1; const float* be1; const float* g2; const float* be2;
    const int* ei; const int* posIn; const float* b3;
    float* outT; float* out;
    unsigned* bar;   // bar[0]=count, bar[1]=generation
};

template<bool FIRST, bool LAST>
__device__ __forceinline__ void layer_body(const FusedArgs& A,
    const float* __restrict__ xe_in, float* __restrict__ xe_out,
    int n, int base, int b, int dIn, int dF, int dO, float x0r,
    float* tile, float* part_s, float* part_ss, float* sc, float* sh)
{
    // ---- Phase A: acc[c] = sum_k xe_in[row(k)+b] * w1s[slot k][c] ----
    float a[CC];
    #pragma unroll
    for (int c = 0; c < CC; c++) a[c] = 0.0f;

    for (int k0 = 0; k0 < dIn; k0 += 16) {
        float v[16];
        #pragma unroll
        for (int j = 0; j < 16; j++) {       // 16 independent loads in flight
            v[j] = 0.0f;
            if (k0 + j < dIn) {              // uniform predicate
                int ro = FIRST ? A.inoff[base + k0 + j] : (base + k0 + j) * BB;
                v[j] = xe_in[ro + b];        // coalesced 512B row
            }
        }
        #pragma unroll
        for (int j = 0; j < 16; j++) {
            if (k0 + j < dIn) {
                const float* wr = &A.w1s[(size_t)(base + k0 + j) * CC]; // uniform -> s_load
                #pragma unroll
                for (int c = 0; c < CC; c++) a[c] += v[j] * wr[c];
            }
        }
    }

    bn_elu(a, A.g1 + n * CC, A.be1 + n * CC, tile, part_s, part_ss, sc, sh, b);

    // ---- 16x16 matmul from registers, wave-uniform weights ----
    float h2[CC];
    #pragma unroll
    for (int d = 0; d < CC; d++) h2[d] = 0.0f;
    const float* w2n = A.w2 + (size_t)n * (CC * CC);
    #pragma unroll
    for (int c = 0; c < CC; c++) {
        float av = a[c];
        #pragma unroll
        for (int d = 0; d < CC; d++) h2[d] += av * w2n[c * CC + d];
    }

    bn_elu(h2, A.g2 + n * CC, A.be2 + n * CC, tile, part_s, part_ss, sc, sh, b);

    // ---- Phase C: push to pre-compacted live out-slots (no dstn/branch) ----
    if (!LAST) {
        for (int q0 = 0; q0 < dF; q0 += 4) {
            #pragma unroll
            for (int j = 0; j < 4; j++) {
                int q = q0 + j;
                if (q >= dF) break;          // uniform
                int sl = base + q;
                const float* wr = &A.w3s[(size_t)sl * CC];   // uniform -> s_load
                float val = A.b3s[sl] + x0r;
                #pragma unroll
                for (int d = 0; d < CC; d++) val += h2[d] * wr[d];
                xe_out[A.wout[sl] + b] = val;
            }
        }
    } else {
        for (int q0 = 0; q0 < dO; q0 += 4) {
            #pragma unroll
            for (int j = 0; j < 4; j++) {
                int q = q0 + j;
                if (q >= dO) break;          // uniform
                int sl = base + SS - 1 - q;
                const float* wr = &A.w3s[(size_t)sl * CC];
                float val = A.b3s[sl] + x0r;
                #pragma unroll
                for (int d = 0; d < CC; d++) val += h2[d] * wr[d];
                atomicAdd(&A.outT[A.wout[sl] + b], val);
            }
        }
    }
}

__global__ __launch_bounds__(128, 4) void k_fused(FusedArgs A)
{
    const int b = threadIdx.x;
    const int n = FUNC_LO + blockIdx.x;     // func nodes only
    const int base = n * SS;

    __shared__ float tile[CC * HP];          // 8.25 KB
    __shared__ float part_s[128], part_ss[128];
    __shared__ float sc[CC], sh[CC];

    const int dIn = A.degIn[n];              // loaded ONCE for all 4 layers
    const int dF  = A.degF[n];
    const int dO  = A.degO[n];
    const float x0r = A.xT[n * BB + b];

    // ---- fill: constant rows for non-func-src edges (valid for every layer) ----
    // Row-disjoint from layer-0's xeA writes (those are func-src rows) and L0
    // neither reads nor writes xeB/outT, so no sync needed before layer 0; the
    // first gsync publishes everything for layer 1.
    for (int e = blockIdx.x; e < EE; e += NBLK) {
        int s = A.ei[e];
        if (s >= FUNC_LO && s < FUNC_HI) continue;   // func src -> layer_body writes it
        int d = A.ei[EE + e];
        float val = A.b3[e] + A.xT[s * BB + b];
        if (d >= FUNC_LO && d < FUNC_HI) {
            int ro = A.posIn[e] * BB;
            A.xeA[ro + b] = val;
            A.xeB[ro + b] = val;
        } else if (d >= OUT_LO) {
            atomicAdd(&A.outT[(d - OUT_LO) * BB + b], val);
        }
    }

    // ---- 4 layers, manual grid-wide sync between ----
    layer_body<true,  false>(A, A.xT,  A.xeA, n, base, b, dIn, dF, dO, x0r,
                             tile, part_s, part_ss, sc, sh);
    gsync(A.bar, A.bar + 1);
    layer_body<false, false>(A, A.xeA, A.xeB, n, base, b, dIn, dF, dO, x0r,
                             tile, part_s, part_ss, sc, sh);
    gsync(A.bar, A.bar + 1);
    layer_body<false, false>(A, A.xeB, A.xeA, n, base, b, dIn, dF, dO, x0r,
                             tile, part_s, part_ss, sc, sh);
    gsync(A.bar, A.bar + 1);
    layer_body<false, true >(A, A.xeA, A.xeB, n, base, b, dIn, dF, dO, x0r,
                             tile, part_s, part_ss, sc, sh);
    gsync(A.bar, A.bar + 1);

    // ---- finalize: out[b*N+n] = (n >= OUT_LO) ? outT[(n-OUT_LO)*B+b] : 0 ----
    for (int t = blockIdx.x * BB + b; t < BB * NN; t += NBLK * BB) {
        int bb = t / NN, nn2 = t - bb * NN;
        A.out[t] = (nn2 >= OUT_LO) ? A.outT[(nn2 - OUT_LO) * BB + bb] : 0.0f;
    }
}

extern "C" void kernel_launch(void* const* d_in, const int* in_sizes, int n_in,
                              void* d_out, int out_size, void* d_ws, size_t ws_size,
                              hipStream_t stream) {
    const float* x   = (const float*)d_in[0];
    const float* w1  = (const float*)d_in[1];
    // d_in[2] = b1: cancels through batchnorm
    const float* w2  = (const float*)d_in[3];
    // d_in[4] = b2: cancels through batchnorm
    const float* w3  = (const float*)d_in[5];
    const float* b3  = (const float*)d_in[6];
    const float* g1  = (const float*)d_in[7];
    const float* be1 = (const float*)d_in[8];
    const float* g2  = (const float*)d_in[9];
    const float* be2 = (const float*)d_in[10];
    const int* ei    = (const int*)d_in[11];
    float* out = (float*)d_out;

    // workspace partition (fixed-stride slot layout, S=40)
    char* ws = (char*)d_ws;
    float* xT   = (float*)ws;  ws += (size_t)NN * BB * 4;            // 1.0 MB
    float* xeA  = (float*)ws;  ws += (size_t)NN * SS * BB * 4;       // 41 MB
    float* xeB  = (float*)ws;  ws += (size_t)NN * SS * BB * 4;       // 41 MB
    float* w1s  = (float*)ws;  ws += (size_t)NN * SS * CC * 4;       // 5.1 MB
    float* w3s  = (float*)ws;  ws += (size_t)NN * SS * CC * 4;       // 5.1 MB
    float* b3s  = (float*)ws;  ws += (size_t)NN * SS * 4;
    float* outT = (float*)ws;  ws += (size_t)OUTN * BB * 4;
    int* degIn  = (int*)ws;    ws += (size_t)NN * 4;                 // contiguous:
    int* degF   = (int*)ws;    ws += (size_t)NN * 4;                 //   degIn,degF,degO,bar
    int* degO   = (int*)ws;    ws += (size_t)NN * 4;                 //   zeroed by ONE memset
    unsigned* bar = (unsigned*)ws; ws += 4 * 4;
    int* posIn  = (int*)ws;    ws += (size_t)EE * 4;
    int* inoff  = (int*)ws;    ws += (size_t)NN * SS * 4;
    int* wout   = (int*)ws;    ws += (size_t)NN * SS * 4;

    hipMemsetAsync(degIn, 0, (3 * NN + 4) * sizeof(int), stream);
    k_prep<<<(NN * BB + 255) / 256, 256, 0, stream>>>(
        x, ei, w1, w3, b3, degIn, degF, degO, posIn,
        xT, w1s, w3s, b3s, inoff, wout, outT);

    FusedArgs fa;
    fa.xT = xT; fa.xeA = xeA; fa.xeB = xeB;
    fa.w1s = w1s; fa.w2 = w2; fa.w3s = w3s; fa.b3s = b3s;
    fa.inoff = inoff; fa.wout = wout;
    fa.degIn = degIn; fa.degF = degF; fa.degO = degO;
    fa.g1 = g1; fa.be1 = be1; fa.g2 = g2; fa.be2 = be2;
    fa.ei = ei; fa.posIn = posIn; fa.b3 = b3;
    fa.outT = outT; fa.out = out;
    fa.bar = bar;
    k_fused<<<NBLK, 128, 0, stream>>>(fa);
}

// Round 3
// 1361.290 us; speedup vs baseline: 1.2363x; 1.2363x over previous
//
#include <hip/hip_runtime.h>
#include <math.h>

// Problem constants (from reference setup_inputs)
#define BB 128        // batch
#define NN 2000       // nodes
#define EE 20000      // edges
#define CC 16         // channels
#define FUNC_LO 200   // func nodes: [200, 1800)
#define FUNC_HI 1800
#define OUT_LO 1800   // output nodes: [1800, 2000)
#define NFUNC 1600
#define NBLK 1600     // fused-kernel grid (1 block per func node)
#define EPSV 1e-5f
#define SS 40         // fixed slots per node per direction (Poisson(10): P(deg>40)~1e-15)
#define HP 129        // padded LDS stride

#define SCOPE_AGENT __HIP_MEMORY_SCOPE_AGENT

// xe rows cross the in-kernel grid barrier between blocks on different XCDs.
// Per-XCD L2s are NOT cross-coherent, so these accesses use agent-scope relaxed
// atomics (IC-coherent, bypass stale L1/L2). They are scalar 4B/lane anyway, so
// no vectorization is lost.
static __device__ __forceinline__ float xe_ld(const float* p) {
    return __hip_atomic_load(p, __ATOMIC_RELAXED, SCOPE_AGENT);
}
static __device__ __forceinline__ void xe_st(float* p, float v) {
    __hip_atomic_store(p, v, __ATOMIC_RELAXED, SCOPE_AGENT);
}

// ---------------- grid barrier v2: flags + detector + broadcast ----------------
// Round-2 post-mortem: 1600 same-address ACQ_REL fetch_adds colliding with 1599
// spinning polls on the SAME cacheline cost ~400us/barrier (18.8 GB of poll
// FETCH). v2: arrivals write 1600 DISTINCT flag words (no contention); block 0
// sweeps them (128 coalesced ILP loads/round); one `gen` word broadcasts, polled
// read-only with s_sleep(32) throttle. All spins bounded -> no hang.
// Co-residency by construction: VGPR<=128 (launch_bounds), LDS 9.7KB ->
// >=8 blocks/CU * 256 CU = 2048 >= 1600; verified round 2 (Occupancy 38.6% =
// exactly 3200/8192 waves resident).
__device__ __forceinline__ void gsync(int* flags, int* gen, int epoch) {
    __syncthreads();   // drains vmcnt: all this block's xe atomic stores are at IC
    if (threadIdx.x == 0)
        __hip_atomic_store(&flags[blockIdx.x], epoch, __ATOMIC_RELEASE, SCOPE_AGENT);
    if (blockIdx.x == 0) {
        int tries = 0; bool ok = false;
        while (!ok) {
            ok = true;
            #pragma unroll 1
            for (int i = threadIdx.x; i < NBLK; i += 128)   // 13 independent loads
                ok &= (__hip_atomic_load(&flags[i], __ATOMIC_ACQUIRE, SCOPE_AGENT) >= epoch);
            if (!ok) { __builtin_amdgcn_s_sleep(4); if (++tries > (1 << 15)) break; }
        }
        __syncthreads();                     // all sweep threads done
        if (threadIdx.x == 0)
            __hip_atomic_store(gen, epoch, __ATOMIC_RELEASE, SCOPE_AGENT);
    } else if (threadIdx.x == 0) {
        int tries = 0;
        while (__hip_atomic_load(gen, __ATOMIC_ACQUIRE, SCOPE_AGENT) < epoch) {
            __builtin_amdgcn_s_sleep(32);    // ~2k cycles: poll traffic ~negligible
            if (++tries > (1 << 15)) break;  // safety valve vs deadlock
        }
    }
    __syncthreads();
}

// ---------------- prep: slot assign + operand gather + transpose + out zero ------
// In-slots: only func-dst edges get one (others are never read).
// Out-slots (func-src only), pre-compacted: func-dst edges fill [0,degF) from the
// front (wout = dst in-slot row); out-dst edges fill from the back (wout = dst
// node id). Input-dst edges get nothing (dead).
__global__ void k_prep(const float* __restrict__ x, const int* __restrict__ ei,
                       const float* __restrict__ w1, const float* __restrict__ w3,
                       const float* __restrict__ b3,
                       int* __restrict__ degIn, int* __restrict__ degF,
                       int* __restrict__ degO, int* __restrict__ posIn,
                       float* __restrict__ xT, float* __restrict__ w1s,
                       float* __restrict__ w3s, float* __restrict__ b3s,
                       int* __restrict__ inoff, int* __restrict__ wout,
                       float* __restrict__ out)
{
    int t = blockIdx.x * 256 + threadIdx.x;
    if (t < EE) {
        int s = ei[t], d = ei[EE + t];
        bool dFn = (d >= FUNC_LO && d < FUNC_HI);
        bool sFn = (s >= FUNC_LO && s < FUNC_HI);
        int pi = -1;
        if (dFn) {                                  // in-slot at dst
            int p = atomicAdd(&degIn[d], 1);
            pi = d * SS + p;
            posIn[t] = pi;
            const float4* w1v = (const float4*)w1 + (size_t)t * 4;
            float4* w1o = (float4*)w1s + (size_t)pi * 4;
            #pragma unroll
            for (int i = 0; i < 4; i++) w1o[i] = w1v[i];
            inoff[pi] = s * BB;                     // layer-0 input row = xT[src]
        }
        if (sFn) {                                  // out-slot at src (live only)
            int po = -1;
            if (dFn) {
                int q = atomicAdd(&degF[s], 1);
                po = s * SS + q;                    // front: func-dst
                wout[po] = pi * BB;                 // write row = dst's in-slot
            } else if (d >= OUT_LO) {
                int q = atomicAdd(&degO[s], 1);
                po = s * SS + (SS - 1 - q);         // back: out-dst
                wout[po] = d;                       // dst node id (for direct out add)
            }
            if (po >= 0) {
                const float4* w3v = (const float4*)w3 + (size_t)t * 4;
                float4* w3o = (float4*)w3s + (size_t)po * 4;
                #pragma unroll
                for (int i = 0; i < 4; i++) w3o[i] = w3v[i];
                b3s[po] = b3[t];
            }
        }
    }
    if (t < NN * BB) {
        out[t] = 0.0f;                 // zero output (no atomics to out here: safe)
        int b = t / NN, n = t - b * NN;
        xT[n * BB + b] = x[t];         // transpose x (B,N) -> xT (N,B)
    }
}

// ---------------- batchnorm + elu over a per-thread register column ----------------
__device__ __forceinline__ void bn_elu(float (&t)[CC],
                                       const float* __restrict__ g,
                                       const float* __restrict__ be,
                                       float* tile, float* part_s, float* part_ss,
                                       float* sc, float* sh, int b) {
    #pragma unroll
    for (int c = 0; c < CC; c++) tile[c * HP + b] = t[c];
    __syncthreads();
    {
        int c = b & 15, grp = b >> 4;          // 16 channels x 8 groups of 16 b
        float s = 0.f, ss = 0.f;
        #pragma unroll
        for (int i = 0; i < 16; i++) {
            float v = tile[c * HP + grp * 16 + i];
            s += v; ss += v * v;
        }
        part_s[grp * 16 + c] = s;
        part_ss[grp * 16 + c] = ss;
    }
    __syncthreads();
    if (b < CC) {
        float S = 0.f, SSm = 0.f;
        #pragma unroll
        for (int g8 = 0; g8 < 8; g8++) { S += part_s[g8 * 16 + b]; SSm += part_ss[g8 * 16 + b]; }
        float mean = S * (1.0f / BB);
        float var = SSm * (1.0f / BB) - mean * mean;
        float scale = rsqrtf(var + EPSV) * g[b];
        sc[b] = scale;
        sh[b] = be[b] - mean * scale;
    }
    __syncthreads();
    #pragma unroll
    for (int c = 0; c < CC; c++) {
        float u = t[c] * sc[c] + sh[c];
        t[c] = (u > 0.0f) ? u : (__expf(u) - 1.0f);
    }
}

// ---------------- fused kernel: fill + 4 layers (3 grid barriers) ----------------
struct FusedArgs {
    const float* xT; float* xeA; float* xeB;
    const float* w1s; const float* w2; const float* w3s; const float* b3s;
    const int* inoff; const int* wout;
    const int* degIn; const int* degF; const int* degO;
    const float* g1; const float* be1; const float* g2; const float* be2;
    const int* ei; const int* posIn; const float* b3;
    float* out;
    int* flags; int* gen;
};

template<bool FIRST, bool LAST>
__device__ __forceinline__ void layer_body(const FusedArgs& A,
    const float* __restrict__ xe_in, float* __restrict__ xe_out,
    int n, int base, int b, int dIn, int dF, int dO, float x0r,
    float* tile, float* part_s, float* part_ss, float* sc, float* sh)
{
    // ---- Phase A: acc[c] = sum_k xe_in[row(k)+b] * w1s[slot k][c] ----
    float a[CC];
    #pragma unroll
    for (int c = 0; c < CC; c++) a[c] = 0.0f;

    for (int k0 = 0; k0 < dIn; k0 += 16) {
        float v[16];
        #pragma unroll
        for (int j = 0; j < 16; j++) {       // 16 independent loads in flight
            v[j] = 0.0f;
            if (k0 + j < dIn) {              // uniform predicate
                int ro = FIRST ? A.inoff[base + k0 + j] : (base + k0 + j) * BB;
                // FIRST reads xT (prior-kernel data, cacheable); later layers read
                // barrier-crossing xe rows -> IC-coherent atomic load.
                v[j] = FIRST ? xe_in[ro + b] : xe_ld(&xe_in[ro + b]);
            }
        }
        #pragma unroll
        for (int j = 0; j < 16; j++) {
            if (k0 + j < dIn) {
                const float* wr = &A.w1s[(size_t)(base + k0 + j) * CC]; // uniform -> s_load
                #pragma unroll
                for (int c = 0; c < CC; c++) a[c] += v[j] * wr[c];
            }
        }
    }

    bn_elu(a, A.g1 + n * CC, A.be1 + n * CC, tile, part_s, part_ss, sc, sh, b);

    // ---- 16x16 matmul from registers, wave-uniform weights ----
    float h2[CC];
    #pragma unroll
    for (int d = 0; d < CC; d++) h2[d] = 0.0f;
    const float* w2n = A.w2 + (size_t)n * (CC * CC);
    #pragma unroll
    for (int c = 0; c < CC; c++) {
        float av = a[c];
        #pragma unroll
        for (int d = 0; d < CC; d++) h2[d] += av * w2n[c * CC + d];
    }

    bn_elu(h2, A.g2 + n * CC, A.be2 + n * CC, tile, part_s, part_ss, sc, sh, b);

    // ---- Phase C: push to pre-compacted live out-slots ----
    if (!LAST) {
        for (int q0 = 0; q0 < dF; q0 += 4) {
            #pragma unroll
            for (int j = 0; j < 4; j++) {
                int q = q0 + j;
                if (q >= dF) break;          // uniform
                int sl = base + q;
                const float* wr = &A.w3s[(size_t)sl * CC];   // uniform -> s_load
                float val = A.b3s[sl] + x0r;
                #pragma unroll
                for (int d = 0; d < CC; d++) val += h2[d] * wr[d];
                xe_st(&xe_out[A.wout[sl] + b], val);
            }
        }
    } else {
        for (int q0 = 0; q0 < dO; q0 += 4) {
            #pragma unroll
            for (int j = 0; j < 4; j++) {
                int q = q0 + j;
                if (q >= dO) break;          // uniform
                int sl = base + SS - 1 - q;
                const float* wr = &A.w3s[(size_t)sl * CC];
                float val = A.b3s[sl] + x0r;
                #pragma unroll
                for (int d = 0; d < CC; d++) val += h2[d] * wr[d];
                int dn = A.wout[sl];         // dst node id
                atomicAdd(&A.out[(size_t)b * NN + dn], val);   // scattered, fire&forget
            }
        }
    }
}

__global__ __launch_bounds__(128, 4) void k_fused(FusedArgs A)
{
    const int b = threadIdx.x;
    const int n = FUNC_LO + blockIdx.x;     // func nodes only
    const int base = n * SS;

    __shared__ float tile[CC * HP];          // 8.25 KB
    __shared__ float part_s[128], part_ss[128];
    __shared__ float sc[CC], sh[CC];

    const int dIn = A.degIn[n];              // loaded ONCE for all 4 layers
    const int dF  = A.degF[n];
    const int dO  = A.degO[n];
    const float x0r = A.xT[n * BB + b];

    // ---- fill: constant rows for non-func-src edges (valid for every layer) ----
    // Row-disjoint from layer-0's xeA writes (those are func-src rows), so no sync
    // needed before layer 0; the first gsync publishes everything for layer 1.
    for (int e = blockIdx.x; e < EE; e += NBLK) {
        int s = A.ei[e];
        if (s >= FUNC_LO && s < FUNC_HI) continue;   // func src -> layer_body writes it
        int d = A.ei[EE + e];
        float val = A.b3[e] + A.xT[s * BB + b];
        if (d >= FUNC_LO && d < FUNC_HI) {
            int ro = A.posIn[e] * BB;
            xe_st(&A.xeA[ro + b], val);
            xe_st(&A.xeB[ro + b], val);
        } else if (d >= OUT_LO) {
            atomicAdd(&A.out[(size_t)b * NN + d], val);
        }
    }

    // ---- 4 layers, contention-free grid sync between ----
    layer_body<true,  false>(A, A.xT,  A.xeA, n, base, b, dIn, dF, dO, x0r,
                             tile, part_s, part_ss, sc, sh);
    gsync(A.flags, A.gen, 1);
    layer_body<false, false>(A, A.xeA, A.xeB, n, base, b, dIn, dF, dO, x0r,
                             tile, part_s, part_ss, sc, sh);
    gsync(A.flags, A.gen, 2);
    layer_body<false, false>(A, A.xeB, A.xeA, n, base, b, dIn, dF, dO, x0r,
                             tile, part_s, part_ss, sc, sh);
    gsync(A.flags, A.gen, 3);
    layer_body<false, true >(A, A.xeA, A.xeB, n, base, b, dIn, dF, dO, x0r,
                             tile, part_s, part_ss, sc, sh);
    // last layer atomic-adds straight into out: no 4th barrier, no finalize needed
}

extern "C" void kernel_launch(void* const* d_in, const int* in_sizes, int n_in,
                              void* d_out, int out_size, void* d_ws, size_t ws_size,
                              hipStream_t stream) {
    const float* x   = (const float*)d_in[0];
    const float* w1  = (const float*)d_in[1];
    // d_in[2] = b1: cancels through batchnorm
    const float* w2  = (const float*)d_in[3];
    // d_in[4] = b2: cancels through batchnorm
    const float* w3  = (const float*)d_in[5];
    const float* b3  = (const float*)d_in[6];
    const float* g1  = (const float*)d_in[7];
    const float* be1 = (const float*)d_in[8];
    const float* g2  = (const float*)d_in[9];
    const float* be2 = (const float*)d_in[10];
    const int* ei    = (const int*)d_in[11];
    float* out = (float*)d_out;

    // workspace partition (fixed-stride slot layout, S=40)
    char* ws = (char*)d_ws;
    float* xT   = (float*)ws;  ws += (size_t)NN * BB * 4;            // 1.0 MB
    float* xeA  = (float*)ws;  ws += (size_t)NN * SS * BB * 4;       // 41 MB
    float* xeB  = (float*)ws;  ws += (size_t)NN * SS * BB * 4;       // 41 MB
    float* w1s  = (float*)ws;  ws += (size_t)NN * SS * CC * 4;       // 5.1 MB
    float* w3s  = (float*)ws;  ws += (size_t)NN * SS * CC * 4;       // 5.1 MB
    float* b3s  = (float*)ws;  ws += (size_t)NN * SS * 4;
    int* degIn  = (int*)ws;    ws += (size_t)NN * 4;                 // contiguous meta:
    int* degF   = (int*)ws;    ws += (size_t)NN * 4;                 //   degIn,degF,degO,
    int* degO   = (int*)ws;    ws += (size_t)NN * 4;                 //   flags,gen zeroed
    int* flags  = (int*)ws;    ws += (size_t)NBLK * 4;               //   by ONE memset
    int* gen    = (int*)ws;    ws += 64;                             // own cacheline
    int* posIn  = (int*)ws;    ws += (size_t)EE * 4;
    int* inoff  = (int*)ws;    ws += (size_t)NN * SS * 4;
    int* wout   = (int*)ws;    ws += (size_t)NN * SS * 4;

    hipMemsetAsync(degIn, 0, (3 * NN + NBLK + 16) * sizeof(int), stream);
    k_prep<<<(NN * BB + 255) / 256, 256, 0, stream>>>(
        x, ei, w1, w3, b3, degIn, degF, degO, posIn,
        xT, w1s, w3s, b3s, inoff, wout, out);

    FusedArgs fa;
    fa.xT = xT; fa.xeA = xeA; fa.xeB = xeB;
    fa.w1s = w1s; fa.w2 = w2; fa.w3s = w3s; fa.b3s = b3s;
    fa.inoff = inoff; fa.wout = wout;
    fa.degIn = degIn; fa.degF = degF; fa.degO = degO;
    fa.g1 = g1; fa.be1 = be1; fa.g2 = g2; fa.be2 = be2;
    fa.ei = ei; fa.posIn = posIn; fa.b3 = b3;
    fa.out = out;
    fa.flags = flags; fa.gen = gen;
    k_fused<<<NBLK, 128, 0, stream>>>(fa);
}

// Round 4
// 210.634 us; speedup vs baseline: 7.9897x; 6.4628x over previous
//
#include <hip/hip_runtime.h>
#include <math.h>

// Problem constants (from reference setup_inputs)
#define BB 128        // batch
#define NN 2000       // nodes
#define EE 20000      // edges
#define CC 16         // channels
#define FUNC_LO 200   // func nodes: [200, 1800)
#define FUNC_HI 1800
#define OUT_LO 1800   // output nodes: [1800, 2000)
#define NFUNC 1600
#define NBLK 1600     // fused-kernel grid (1 block per func node)
#define EPSV 1e-5f
#define SS 40         // fixed slots per node per direction (Poisson(10): P(deg>40)~1e-15)
#define HP 129        // padded LDS stride

#define SCOPE_AGENT __HIP_MEMORY_SCOPE_AGENT

// xe rows cross the in-kernel grid barrier between blocks on different XCDs.
// Per-XCD L2s are NOT cross-coherent, so these accesses use agent-scope RELAXED
// atomics: performed at the coherence point (IC), bypassing stale L1/L2, with
// NO fence instructions (no buffer_wbl2 / buffer_inv). Scalar 4B/lane anyway.
static __device__ __forceinline__ float xe_ld(const float* p) {
    return __hip_atomic_load(p, __ATOMIC_RELAXED, SCOPE_AGENT);
}
static __device__ __forceinline__ void xe_st(float* p, float v) {
    __hip_atomic_store(p, v, __ATOMIC_RELAXED, SCOPE_AGENT);
}

// ---------------- grid barrier v3: ALL-RELAXED flags + detector + broadcast -------
// Round-2/3 post-mortem: per-barrier cost was ~450-480us and INVARIANT to arrival
// contention, poll rate, and flag layout. Common factor: RELEASE/ACQUIRE lowering
// at agent scope = buffer_wbl2 (full-L2 writeback) per release and buffer_inv
// (full-L2 invalidate) per acquire -> ~1600 L2 writebacks per barrier. Those
// fences are redundant here: all barrier-crossing data moves via agent-relaxed
// atomics performed AT the IC, so ordering only needs "data stores ACKed before
// flag store issues" = explicit s_waitcnt vmcnt(0). v3 is fence-free:
//   arrival: vmcnt(0) drain, then RELAXED flag store (1600 distinct words)
//   detect:  block 0 sweeps flags with RELAXED loads (13 pipelined loads/thread)
//   bcast:   RELAXED gen store; waiters RELAXED-poll with s_sleep(8) throttle
// All spins bounded -> no hang. Co-residency by construction: VGPR<=128
// (launch_bounds), LDS 9.7KB -> 8 blocks/CU * 256 CU = 2048 >= 1600; verified
// rounds 2-3 (Occupancy 38.3-38.7% == 3200/8192 waves resident).
__device__ __forceinline__ void gsync(int* flags, int* gen, int epoch) {
    __syncthreads();
    if (threadIdx.x == 0) {
        asm volatile("s_waitcnt vmcnt(0)" ::: "memory");  // xe stores ACKed at IC
        __hip_atomic_store(&flags[blockIdx.x], epoch, __ATOMIC_RELAXED, SCOPE_AGENT);
    }
    if (blockIdx.x == 0) {
        int tries = 0; bool ok = false;
        while (!ok) {
            ok = true;
            #pragma unroll 1
            for (int i = threadIdx.x; i < NBLK; i += 128)   // 13 pipelined IC loads
                ok &= (__hip_atomic_load(&flags[i], __ATOMIC_RELAXED, SCOPE_AGENT) >= epoch);
            if (!ok) { __builtin_amdgcn_s_sleep(1); if (++tries > (1 << 16)) break; }
        }
        __syncthreads();                     // all sweep threads done
        if (threadIdx.x == 0)
            __hip_atomic_store(gen, epoch, __ATOMIC_RELAXED, SCOPE_AGENT);
    } else if (threadIdx.x == 0) {
        int tries = 0;
        while (__hip_atomic_load(gen, __ATOMIC_RELAXED, SCOPE_AGENT) < epoch) {
            __builtin_amdgcn_s_sleep(8);     // ~0.2us poll interval, read-only
            if (++tries > (1 << 17)) break;  // safety valve vs deadlock
        }
    }
    __syncthreads();
}

// ---------------- prep: slot assign + operand gather + transpose + out zero ------
// In-slots: only func-dst edges get one (others are never read).
// Out-slots (func-src only), pre-compacted: func-dst edges fill [0,degF) from the
// front (wout = dst in-slot row); out-dst edges fill from the back (wout = dst
// node id). Input-dst edges get nothing (dead).
__global__ void k_prep(const float* __restrict__ x, const int* __restrict__ ei,
                       const float* __restrict__ w1, const float* __restrict__ w3,
                       const float* __restrict__ b3,
                       int* __restrict__ degIn, int* __restrict__ degF,
                       int* __restrict__ degO, int* __restrict__ posIn,
                       float* __restrict__ xT, float* __restrict__ w1s,
                       float* __restrict__ w3s, float* __restrict__ b3s,
                       int* __restrict__ inoff, int* __restrict__ wout,
                       float* __restrict__ out)
{
    int t = blockIdx.x * 256 + threadIdx.x;
    if (t < EE) {
        int s = ei[t], d = ei[EE + t];
        bool dFn = (d >= FUNC_LO && d < FUNC_HI);
        bool sFn = (s >= FUNC_LO && s < FUNC_HI);
        int pi = -1;
        if (dFn) {                                  // in-slot at dst
            int p = atomicAdd(&degIn[d], 1);
            pi = d * SS + p;
            posIn[t] = pi;
            const float4* w1v = (const float4*)w1 + (size_t)t * 4;
            float4* w1o = (float4*)w1s + (size_t)pi * 4;
            #pragma unroll
            for (int i = 0; i < 4; i++) w1o[i] = w1v[i];
            inoff[pi] = s * BB;                     // layer-0 input row = xT[src]
        }
        if (sFn) {                                  // out-slot at src (live only)
            int po = -1;
            if (dFn) {
                int q = atomicAdd(&degF[s], 1);
                po = s * SS + q;                    // front: func-dst
                wout[po] = pi * BB;                 // write row = dst's in-slot
            } else if (d >= OUT_LO) {
                int q = atomicAdd(&degO[s], 1);
                po = s * SS + (SS - 1 - q);         // back: out-dst
                wout[po] = d;                       // dst node id (for direct out add)
            }
            if (po >= 0) {
                const float4* w3v = (const float4*)w3 + (size_t)t * 4;
                float4* w3o = (float4*)w3s + (size_t)po * 4;
                #pragma unroll
                for (int i = 0; i < 4; i++) w3o[i] = w3v[i];
                b3s[po] = b3[t];
            }
        }
    }
    if (t < NN * BB) {
        out[t] = 0.0f;                 // zero output (no atomics to out here: safe)
        int b = t / NN, n = t - b * NN;
        xT[n * BB + b] = x[t];         // transpose x (B,N) -> xT (N,B)
    }
}

// ---------------- batchnorm + elu over a per-thread register column ----------------
__device__ __forceinline__ void bn_elu(float (&t)[CC],
                                       const float* __restrict__ g,
                                       const float* __restrict__ be,
                                       float* tile, float* part_s, float* part_ss,
                                       float* sc, float* sh, int b) {
    #pragma unroll
    for (int c = 0; c < CC; c++) tile[c * HP + b] = t[c];
    __syncthreads();
    {
        int c = b & 15, grp = b >> 4;          // 16 channels x 8 groups of 16 b
        float s = 0.f, ss = 0.f;
        #pragma unroll
        for (int i = 0; i < 16; i++) {
            float v = tile[c * HP + grp * 16 + i];
            s += v; ss += v * v;
        }
        part_s[grp * 16 + c] = s;
        part_ss[grp * 16 + c] = ss;
    }
    __syncthreads();
    if (b < CC) {
        float S = 0.f, SSm = 0.f;
        #pragma unroll
        for (int g8 = 0; g8 < 8; g8++) { S += part_s[g8 * 16 + b]; SSm += part_ss[g8 * 16 + b]; }
        float mean = S * (1.0f / BB);
        float var = SSm * (1.0f / BB) - mean * mean;
        float scale = rsqrtf(var + EPSV) * g[b];
        sc[b] = scale;
        sh[b] = be[b] - mean * scale;
    }
    __syncthreads();
    #pragma unroll
    for (int c = 0; c < CC; c++) {
        float u = t[c] * sc[c] + sh[c];
        t[c] = (u > 0.0f) ? u : (__expf(u) - 1.0f);
    }
}

// ---------------- fused kernel: fill + 4 layers (3 grid barriers) ----------------
struct FusedArgs {
    const float* xT; float* xeA; float* xeB;
    const float* w1s; const float* w2; const float* w3s; const float* b3s;
    const int* inoff; const int* wout;
    const int* degIn; const int* degF; const int* degO;
    const float* g1; const float* be1; const float* g2; const float* be2;
    const int* ei; const int* posIn; const float* b3;
    float* out;
    int* flags; int* gen;
};

template<bool FIRST, bool LAST>
__device__ __forceinline__ void layer_body(const FusedArgs& A,
    const float* __restrict__ xe_in, float* __restrict__ xe_out,
    int n, int base, int b, int dIn, int dF, int dO, float x0r,
    float* tile, float* part_s, float* part_ss, float* sc, float* sh)
{
    // ---- Phase A: acc[c] = sum_k xe_in[row(k)+b] * w1s[slot k][c] ----
    float a[CC];
    #pragma unroll
    for (int c = 0; c < CC; c++) a[c] = 0.0f;

    for (int k0 = 0; k0 < dIn; k0 += 16) {
        float v[16];
        #pragma unroll
        for (int j = 0; j < 16; j++) {       // 16 independent loads in flight
            v[j] = 0.0f;
            if (k0 + j < dIn) {              // uniform predicate
                int ro = FIRST ? A.inoff[base + k0 + j] : (base + k0 + j) * BB;
                // FIRST reads xT (prior-kernel data, cacheable); later layers read
                // barrier-crossing xe rows -> IC-coherent relaxed atomic load.
                v[j] = FIRST ? xe_in[ro + b] : xe_ld(&xe_in[ro + b]);
            }
        }
        #pragma unroll
        for (int j = 0; j < 16; j++) {
            if (k0 + j < dIn) {
                const float* wr = &A.w1s[(size_t)(base + k0 + j) * CC]; // uniform -> s_load
                #pragma unroll
                for (int c = 0; c < CC; c++) a[c] += v[j] * wr[c];
            }
        }
    }

    bn_elu(a, A.g1 + n * CC, A.be1 + n * CC, tile, part_s, part_ss, sc, sh, b);

    // ---- 16x16 matmul from registers, wave-uniform weights ----
    float h2[CC];
    #pragma unroll
    for (int d = 0; d < CC; d++) h2[d] = 0.0f;
    const float* w2n = A.w2 + (size_t)n * (CC * CC);
    #pragma unroll
    for (int c = 0; c < CC; c++) {
        float av = a[c];
        #pragma unroll
        for (int d = 0; d < CC; d++) h2[d] += av * w2n[c * CC + d];
    }

    bn_elu(h2, A.g2 + n * CC, A.be2 + n * CC, tile, part_s, part_ss, sc, sh, b);

    // ---- Phase C: push to pre-compacted live out-slots ----
    if (!LAST) {
        for (int q0 = 0; q0 < dF; q0 += 4) {
            #pragma unroll
            for (int j = 0; j < 4; j++) {
                int q = q0 + j;
                if (q >= dF) break;          // uniform
                int sl = base + q;
                const float* wr = &A.w3s[(size_t)sl * CC];   // uniform -> s_load
                float val = A.b3s[sl] + x0r;
                #pragma unroll
                for (int d = 0; d < CC; d++) val += h2[d] * wr[d];
                xe_st(&xe_out[A.wout[sl] + b], val);
            }
        }
    } else {
        for (int q0 = 0; q0 < dO; q0 += 4) {
            #pragma unroll
            for (int j = 0; j < 4; j++) {
                int q = q0 + j;
                if (q >= dO) break;          // uniform
                int sl = base + SS - 1 - q;
                const float* wr = &A.w3s[(size_t)sl * CC];
                float val = A.b3s[sl] + x0r;
                #pragma unroll
                for (int d = 0; d < CC; d++) val += h2[d] * wr[d];
                int dn = A.wout[sl];         // dst node id
                atomicAdd(&A.out[(size_t)b * NN + dn], val);   // scattered, fire&forget
            }
        }
    }
}

__global__ __launch_bounds__(128, 4) void k_fused(FusedArgs A)
{
    const int b = threadIdx.x;
    const int n = FUNC_LO + blockIdx.x;     // func nodes only
    const int base = n * SS;

    __shared__ float tile[CC * HP];          // 8.25 KB
    __shared__ float part_s[128], part_ss[128];
    __shared__ float sc[CC], sh[CC];

    const int dIn = A.degIn[n];              // loaded ONCE for all 4 layers
    const int dF  = A.degF[n];
    const int dO  = A.degO[n];
    const float x0r = A.xT[n * BB + b];

    // ---- fill: constant rows for non-func-src edges (valid for every layer) ----
    // Row-disjoint from layer-0's xeA writes (those are func-src rows), so no sync
    // needed before layer 0; the first gsync publishes everything for layer 1.
    for (int e = blockIdx.x; e < EE; e += NBLK) {
        int s = A.ei[e];
        if (s >= FUNC_LO && s < FUNC_HI) continue;   // func src -> layer_body writes it
        int d = A.ei[EE + e];
        float val = A.b3[e] + A.xT[s * BB + b];
        if (d >= FUNC_LO && d < FUNC_HI) {
            int ro = A.posIn[e] * BB;
            xe_st(&A.xeA[ro + b], val);
            xe_st(&A.xeB[ro + b], val);
        } else if (d >= OUT_LO) {
            atomicAdd(&A.out[(size_t)b * NN + d], val);
        }
    }

    // ---- 4 layers, fence-free grid sync between ----
    layer_body<true,  false>(A, A.xT,  A.xeA, n, base, b, dIn, dF, dO, x0r,
                             tile, part_s, part_ss, sc, sh);
    gsync(A.flags, A.gen, 1);
    layer_body<false, false>(A, A.xeA, A.xeB, n, base, b, dIn, dF, dO, x0r,
                             tile, part_s, part_ss, sc, sh);
    gsync(A.flags, A.gen, 2);
    layer_body<false, false>(A, A.xeB, A.xeA, n, base, b, dIn, dF, dO, x0r,
                             tile, part_s, part_ss, sc, sh);
    gsync(A.flags, A.gen, 3);
    layer_body<false, true >(A, A.xeA, A.xeB, n, base, b, dIn, dF, dO, x0r,
                             tile, part_s, part_ss, sc, sh);
    // last layer atomic-adds straight into out: no 4th barrier, no finalize needed
}

extern "C" void kernel_launch(void* const* d_in, const int* in_sizes, int n_in,
                              void* d_out, int out_size, void* d_ws, size_t ws_size,
                              hipStream_t stream) {
    const float* x   = (const float*)d_in[0];
    const float* w1  = (const float*)d_in[1];
    // d_in[2] = b1: cancels through batchnorm
    const float* w2  = (const float*)d_in[3];
    // d_in[4] = b2: cancels through batchnorm
    const float* w3  = (const float*)d_in[5];
    const float* b3  = (const float*)d_in[6];
    const float* g1  = (const float*)d_in[7];
    const float* be1 = (const float*)d_in[8];
    const float* g2  = (const float*)d_in[9];
    const float* be2 = (const float*)d_in[10];
    const int* ei    = (const int*)d_in[11];
    float* out = (float*)d_out;

    // workspace partition (fixed-stride slot layout, S=40)
    char* ws = (char*)d_ws;
    float* xT   = (float*)ws;  ws += (size_t)NN * BB * 4;            // 1.0 MB
    float* xeA  = (float*)ws;  ws += (size_t)NN * SS * BB * 4;       // 41 MB
    float* xeB  = (float*)ws;  ws += (size_t)NN * SS * BB * 4;       // 41 MB
    float* w1s  = (float*)ws;  ws += (size_t)NN * SS * CC * 4;       // 5.1 MB
    float* w3s  = (float*)ws;  ws += (size_t)NN * SS * CC * 4;       // 5.1 MB
    float* b3s  = (float*)ws;  ws += (size_t)NN * SS * 4;
    int* degIn  = (int*)ws;    ws += (size_t)NN * 4;                 // contiguous meta:
    int* degF   = (int*)ws;    ws += (size_t)NN * 4;                 //   degIn,degF,degO,
    int* degO   = (int*)ws;    ws += (size_t)NN * 4;                 //   flags,gen zeroed
    int* flags  = (int*)ws;    ws += (size_t)NBLK * 4;               //   by ONE memset
    int* gen    = (int*)ws;    ws += 64;                             // own cacheline
    int* posIn  = (int*)ws;    ws += (size_t)EE * 4;
    int* inoff  = (int*)ws;    ws += (size_t)NN * SS * 4;
    int* wout   = (int*)ws;    ws += (size_t)NN * SS * 4;

    hipMemsetAsync(degIn, 0, (3 * NN + NBLK + 16) * sizeof(int), stream);
    k_prep<<<(NN * BB + 255) / 256, 256, 0, stream>>>(
        x, ei, w1, w3, b3, degIn, degF, degO, posIn,
        xT, w1s, w3s, b3s, inoff, wout, out);

    FusedArgs fa;
    fa.xT = xT; fa.xeA = xeA; fa.xeB = xeB;
    fa.w1s = w1s; fa.w2 = w2; fa.w3s = w3s; fa.b3s = b3s;
    fa.inoff = inoff; fa.wout = wout;
    fa.degIn = degIn; fa.degF = degF; fa.degO = degO;
    fa.g1 = g1; fa.be1 = be1; fa.g2 = g2; fa.be2 = be2;
    fa.ei = ei; fa.posIn = posIn; fa.b3 = b3;
    fa.out = out;
    fa.flags = flags; fa.gen = gen;
    k_fused<<<NBLK, 128, 0, stream>>>(fa);
}

// Round 5
// 208.873 us; speedup vs baseline: 8.0570x; 1.0084x over previous
//
#include <hip/hip_runtime.h>
#include <math.h>

// Problem constants (from reference setup_inputs)
#define BB 128        // batch
#define NN 2000       // nodes
#define EE 20000      // edges
#define CC 16         // channels
#define FUNC_LO 200   // func nodes: [200, 1800)
#define FUNC_HI 1800
#define OUT_LO 1800   // output nodes: [1800, 2000)
#define NFUNC 1600
#define NBLK 1600     // fused-kernel grid (1 block per func node)
#define EPSV 1e-5f
#define SS 40         // fixed slots per func node per direction (Poisson(10) tail safe)
#define NSLOT (NFUNC * SS)   // compact slot space: func nodes only
#define HP 129        // padded LDS stride

#define SCOPE_AGENT __HIP_MEMORY_SCOPE_AGENT

// ---- xe coherence scheme (round-5) ----
// STORES: relaxed agent-scope atomics -> write-through to IC, never dirty in a
//   local L2, no fence instructions (round-4 validated; fences cost 450us/barrier).
// LOADS:  PLAIN cached loads. Safe because xe is TRIPLE-buffered: each buffer is
//   read by exactly one layer, so every cacheline is first-touch within the
//   dispatch (L2 fill comes from IC = fresh). Cross-dispatch freshness is given
//   by dispatch-boundary invalidate (proven by the round-0 multi-kernel pipeline
//   on this harness). Plain loads restore wave-level coalescing (64 lanes x 4B
//   -> 256B transactions) that per-lane atomic loads may defeat.
static __device__ __forceinline__ void xe_st(float* p, float v) {
    __hip_atomic_store(p, v, __ATOMIC_RELAXED, SCOPE_AGENT);
}

// ---------------- grid barrier (round-4 validated, fence-free) ----------------
//   arrival: per-wave vmcnt drain at __syncthreads, RELAXED flag store (1600 words)
//   detect:  block 0 sweeps flags with RELAXED pipelined loads
//   bcast:   RELAXED gen store; waiters poll with s_sleep(8)
// All spins bounded -> no hang. Co-residency: VGPR<=128, LDS 9.7KB -> 8 blk/CU
// * 256 CU = 2048 >= 1600 (verified: occupancy == all waves resident, rounds 2-4).
__device__ __forceinline__ void gsync(int* flags, int* gen, int epoch) {
    __syncthreads();   // compiler emits s_waitcnt vmcnt(0) per wave before barrier
    if (threadIdx.x == 0) {
        asm volatile("s_waitcnt vmcnt(0)" ::: "memory");
        __hip_atomic_store(&flags[blockIdx.x], epoch, __ATOMIC_RELAXED, SCOPE_AGENT);
    }
    if (blockIdx.x == 0) {
        int tries = 0; bool ok = false;
        while (!ok) {
            ok = true;
            #pragma unroll 1
            for (int i = threadIdx.x; i < NBLK; i += 128)   // 13 pipelined IC loads
                ok &= (__hip_atomic_load(&flags[i], __ATOMIC_RELAXED, SCOPE_AGENT) >= epoch);
            if (!ok) { __builtin_amdgcn_s_sleep(1); if (++tries > (1 << 16)) break; }
        }
        __syncthreads();
        if (threadIdx.x == 0)
            __hip_atomic_store(gen, epoch, __ATOMIC_RELAXED, SCOPE_AGENT);
    } else if (threadIdx.x == 0) {
        int tries = 0;
        while (__hip_atomic_load(gen, __ATOMIC_RELAXED, SCOPE_AGENT) < epoch) {
            __builtin_amdgcn_s_sleep(8);
            if (++tries > (1 << 17)) break;  // safety valve vs deadlock
        }
    }
    __syncthreads();
}

// ---------------- prep: slot assign + operand gather + transpose + out zero ------
// Compact slot space: slots exist only for func nodes; in-slot pi for edge e =
// (d-FUNC_LO)*SS + rank (func-dst edges only). Out-slots at func src,
// pre-compacted: func-dst edges fill from the front (wout = dst in-slot row);
// out-dst edges fill from the back (wout = dst node id). Dead edges get nothing.
__global__ void k_prep(const float* __restrict__ x, const int* __restrict__ ei,
                       const float* __restrict__ w1, const float* __restrict__ w3,
                       const float* __restrict__ b3,
                       int* __restrict__ degIn, int* __restrict__ degF,
                       int* __restrict__ degO, int* __restrict__ posIn,
                       float* __restrict__ xT, float* __restrict__ w1s,
                       float* __restrict__ w3s, float* __restrict__ b3s,
                       int* __restrict__ inoff, int* __restrict__ wout,
                       float* __restrict__ out)
{
    int t = blockIdx.x * 256 + threadIdx.x;
    if (t < EE) {
        int s = ei[t], d = ei[EE + t];
        bool dFn = (d >= FUNC_LO && d < FUNC_HI);
        bool sFn = (s >= FUNC_LO && s < FUNC_HI);
        int pi = -1;
        if (dFn) {                                  // in-slot at dst (compact)
            int p = atomicAdd(&degIn[d], 1);
            pi = (d - FUNC_LO) * SS + p;
            posIn[t] = pi;
            const float4* w1v = (const float4*)w1 + (size_t)t * 4;
            float4* w1o = (float4*)w1s + (size_t)pi * 4;
            #pragma unroll
            for (int i = 0; i < 4; i++) w1o[i] = w1v[i];
            inoff[pi] = s * BB;                     // layer-0 input row = xT[src]
        }
        if (sFn) {                                  // out-slot at src (live only)
            int po = -1;
            if (dFn) {
                int q = atomicAdd(&degF[s], 1);
                po = (s - FUNC_LO) * SS + q;        // front: func-dst
                wout[po] = pi * BB;                 // write row = dst's in-slot
            } else if (d >= OUT_LO) {
                int q = atomicAdd(&degO[s], 1);
                po = (s - FUNC_LO) * SS + (SS - 1 - q);  // back: out-dst
                wout[po] = d;                       // dst node id (direct out add)
            }
            if (po >= 0) {
                const float4* w3v = (const float4*)w3 + (size_t)t * 4;
                float4* w3o = (float4*)w3s + (size_t)po * 4;
                #pragma unroll
                for (int i = 0; i < 4; i++) w3o[i] = w3v[i];
                b3s[po] = b3[t];
            }
        }
    }
    if (t < NN * BB) {
        out[t] = 0.0f;                 // zero output (no atomics to out here: safe)
        int n = t >> 7, b = t & (BB - 1);
        xT[t] = x[b * NN + n];         // coalesced WRITE; scattered read (x is 1MB,
    }                                  // L2/L3-resident)
}

// ---------------- batchnorm + elu over a per-thread register column ----------------
__device__ __forceinline__ void bn_elu(float (&t)[CC],
                                       const float* __restrict__ g,
                                       const float* __restrict__ be,
                                       float* tile, float* part_s, float* part_ss,
                                       float* sc, float* sh, int b) {
    #pragma unroll
    for (int c = 0; c < CC; c++) tile[c * HP + b] = t[c];
    __syncthreads();
    {
        int c = b & 15, grp = b >> 4;          // 16 channels x 8 groups of 16 b
        float s = 0.f, ss = 0.f;
        #pragma unroll
        for (int i = 0; i < 16; i++) {
            float v = tile[c * HP + grp * 16 + i];
            s += v; ss += v * v;
        }
        part_s[grp * 16 + c] = s;
        part_ss[grp * 16 + c] = ss;
    }
    __syncthreads();
    if (b < CC) {
        float S = 0.f, SSm = 0.f;
        #pragma unroll
        for (int g8 = 0; g8 < 8; g8++) { S += part_s[g8 * 16 + b]; SSm += part_ss[g8 * 16 + b]; }
        float mean = S * (1.0f / BB);
        float var = SSm * (1.0f / BB) - mean * mean;
        float scale = rsqrtf(var + EPSV) * g[b];
        sc[b] = scale;
        sh[b] = be[b] - mean * scale;
    }
    __syncthreads();
    #pragma unroll
    for (int c = 0; c < CC; c++) {
        float u = t[c] * sc[c] + sh[c];
        t[c] = (u > 0.0f) ? u : (__expf(u) - 1.0f);
    }
}

// ---------------- fused kernel: fill + 4 layers (3 grid barriers) ----------------
struct FusedArgs {
    const float* xT; float* xeA; float* xeB; float* xeC;
    const float* w1s; const float* w2; const float* w3s; const float* b3s;
    const int* inoff; const int* wout;
    const int* degIn; const int* degF; const int* degO;
    const float* g1; const float* be1; const float* g2; const float* be2;
    const int* ei; const int* posIn; const float* b3;
    float* out;
    int* flags; int* gen;
};

template<bool FIRST, bool LAST>
__device__ __forceinline__ void layer_body(const FusedArgs& A,
    const float* __restrict__ xe_in, float* __restrict__ xe_out,
    int n, int cbase, int b, int dIn, int dF, int dO, float x0r,
    float* tile, float* part_s, float* part_ss, float* sc, float* sh)
{
    // ---- Phase A: acc[c] = sum_k xe_in[row(k)+b] * w1s[slot k][c] ----
    // Plain cached loads: coalesced 256B/wave; first-touch-per-dispatch (see top).
    float a[CC];
    #pragma unroll
    for (int c = 0; c < CC; c++) a[c] = 0.0f;

    for (int k0 = 0; k0 < dIn; k0 += 16) {
        float v[16];
        #pragma unroll
        for (int j = 0; j < 16; j++) {       // 16 independent loads in flight
            v[j] = 0.0f;
            if (k0 + j < dIn) {              // uniform predicate
                int ro = FIRST ? A.inoff[cbase + k0 + j] : (cbase + k0 + j) * BB;
                v[j] = xe_in[ro + b];        // coalesced 512B row
            }
        }
        #pragma unroll
        for (int j = 0; j < 16; j++) {
            if (k0 + j < dIn) {
                const float* wr = &A.w1s[(size_t)(cbase + k0 + j) * CC]; // uniform -> s_load
                #pragma unroll
                for (int c = 0; c < CC; c++) a[c] += v[j] * wr[c];
            }
        }
    }

    bn_elu(a, A.g1 + n * CC, A.be1 + n * CC, tile, part_s, part_ss, sc, sh, b);

    // ---- 16x16 matmul from registers, wave-uniform weights ----
    float h2[CC];
    #pragma unroll
    for (int d = 0; d < CC; d++) h2[d] = 0.0f;
    const float* w2n = A.w2 + (size_t)n * (CC * CC);
    #pragma unroll
    for (int c = 0; c < CC; c++) {
        float av = a[c];
        #pragma unroll
        for (int d = 0; d < CC; d++) h2[d] += av * w2n[c * CC + d];
    }

    bn_elu(h2, A.g2 + n * CC, A.be2 + n * CC, tile, part_s, part_ss, sc, sh, b);

    // ---- Phase C: push to pre-compacted live out-slots (IC write-through) ----
    if (!LAST) {
        for (int q0 = 0; q0 < dF; q0 += 4) {
            #pragma unroll
            for (int j = 0; j < 4; j++) {
                int q = q0 + j;
                if (q >= dF) break;          // uniform
                int sl = cbase + q;
                const float* wr = &A.w3s[(size_t)sl * CC];   // uniform -> s_load
                float val = A.b3s[sl] + x0r;
                #pragma unroll
                for (int d = 0; d < CC; d++) val += h2[d] * wr[d];
                xe_st(&xe_out[A.wout[sl] + b], val);
            }
        }
    } else {
        for (int q0 = 0; q0 < dO; q0 += 4) {
            #pragma unroll
            for (int j = 0; j < 4; j++) {
                int q = q0 + j;
                if (q >= dO) break;          // uniform
                int sl = cbase + SS - 1 - q;
                const float* wr = &A.w3s[(size_t)sl * CC];
                float val = A.b3s[sl] + x0r;
                #pragma unroll
                for (int d = 0; d < CC; d++) val += h2[d] * wr[d];
                int dn = A.wout[sl];         // dst node id
                atomicAdd(&A.out[(size_t)b * NN + dn], val);   // scattered, fire&forget
            }
        }
    }
}

__global__ __launch_bounds__(128, 4) void k_fused(FusedArgs A)
{
    const int b = threadIdx.x;
    const int n = FUNC_LO + blockIdx.x;     // func nodes only
    const int cbase = blockIdx.x * SS;      // compact slot base

    __shared__ float tile[CC * HP];          // 8.25 KB
    __shared__ float part_s[128], part_ss[128];
    __shared__ float sc[CC], sh[CC];

    const int dIn = A.degIn[n];              // loaded ONCE for all 4 layers
    const int dF  = A.degF[n];
    const int dO  = A.degO[n];
    const float x0r = A.xT[n * BB + b];

    // ---- fill: constant rows for non-func-src edges (same value every layer) ----
    // Row-disjoint from layer-0's xeA writes (those are func-src rows), so no sync
    // needed before layer 0; the first gsync publishes everything for layer 1.
    for (int e = blockIdx.x; e < EE; e += NBLK) {
        int s = A.ei[e];
        if (s >= FUNC_LO && s < FUNC_HI) continue;   // func src -> layer_body writes it
        int d = A.ei[EE + e];
        float val = A.b3[e] + A.xT[s * BB + b];
        if (d >= FUNC_LO && d < FUNC_HI) {
            int ro = A.posIn[e] * BB;
            xe_st(&A.xeA[ro + b], val);
            xe_st(&A.xeB[ro + b], val);
            xe_st(&A.xeC[ro + b], val);
        } else if (d >= OUT_LO) {
            atomicAdd(&A.out[(size_t)b * NN + d], val);
        }
    }

    // ---- 4 layers; triple-buffered xe so each buffer is read by ONE layer ----
    layer_body<true,  false>(A, A.xT,  A.xeA, n, cbase, b, dIn, dF, dO, x0r,
                             tile, part_s, part_ss, sc, sh);
    gsync(A.flags, A.gen, 1);
    layer_body<false, false>(A, A.xeA, A.xeB, n, cbase, b, dIn, dF, dO, x0r,
                             tile, part_s, part_ss, sc, sh);
    gsync(A.flags, A.gen, 2);
    layer_body<false, false>(A, A.xeB, A.xeC, n, cbase, b, dIn, dF, dO, x0r,
                             tile, part_s, part_ss, sc, sh);
    gsync(A.flags, A.gen, 3);
    layer_body<false, true >(A, A.xeC, nullptr, n, cbase, b, dIn, dF, dO, x0r,
                             tile, part_s, part_ss, sc, sh);
    // last layer atomic-adds straight into out: no 4th barrier, no finalize needed
}

extern "C" void kernel_launch(void* const* d_in, const int* in_sizes, int n_in,
                              void* d_out, int out_size, void* d_ws, size_t ws_size,
                              hipStream_t stream) {
    const float* x   = (const float*)d_in[0];
    const float* w1  = (const float*)d_in[1];
    // d_in[2] = b1: cancels through batchnorm
    const float* w2  = (const float*)d_in[3];
    // d_in[4] = b2: cancels through batchnorm
    const float* w3  = (const float*)d_in[5];
    const float* b3  = (const float*)d_in[6];
    const float* g1  = (const float*)d_in[7];
    const float* be1 = (const float*)d_in[8];
    const float* g2  = (const float*)d_in[9];
    const float* be2 = (const float*)d_in[10];
    const int* ei    = (const int*)d_in[11];
    float* out = (float*)d_out;

    // workspace partition (compact slot layout: NSLOT = 1600*40 = 64000 rows)
    char* ws = (char*)d_ws;
    float* xT   = (float*)ws;  ws += (size_t)NN * BB * 4;            // 1.0 MB
    float* xeA  = (float*)ws;  ws += (size_t)NSLOT * BB * 4;         // 32.8 MB
    float* xeB  = (float*)ws;  ws += (size_t)NSLOT * BB * 4;         // 32.8 MB
    float* xeC  = (float*)ws;  ws += (size_t)NSLOT * BB * 4;         // 32.8 MB
    float* w1s  = (float*)ws;  ws += (size_t)NSLOT * CC * 4;         // 4.1 MB
    float* w3s  = (float*)ws;  ws += (size_t)NSLOT * CC * 4;         // 4.1 MB
    float* b3s  = (float*)ws;  ws += (size_t)NSLOT * 4;
    int* degIn  = (int*)ws;    ws += (size_t)NN * 4;                 // contiguous meta:
    int* degF   = (int*)ws;    ws += (size_t)NN * 4;                 //   degIn,degF,degO,
    int* degO   = (int*)ws;    ws += (size_t)NN * 4;                 //   flags,gen zeroed
    int* flags  = (int*)ws;    ws += (size_t)NBLK * 4;               //   by ONE memset
    int* gen    = (int*)ws;    ws += 64;                             // own cacheline
    int* posIn  = (int*)ws;    ws += (size_t)EE * 4;
    int* inoff  = (int*)ws;    ws += (size_t)NSLOT * 4;
    int* wout   = (int*)ws;    ws += (size_t)NSLOT * 4;

    hipMemsetAsync(degIn, 0, (3 * NN + NBLK + 16) * sizeof(int), stream);
    k_prep<<<(NN * BB + 255) / 256, 256, 0, stream>>>(
        x, ei, w1, w3, b3, degIn, degF, degO, posIn,
        xT, w1s, w3s, b3s, inoff, wout, out);

    FusedArgs fa;
    fa.xT = xT; fa.xeA = xeA; fa.xeB = xeB; fa.xeC = xeC;
    fa.w1s = w1s; fa.w2 = w2; fa.w3s = w3s; fa.b3s = b3s;
    fa.inoff = inoff; fa.wout = wout;
    fa.degIn = degIn; fa.degF = degF; fa.degO = degO;
    fa.g1 = g1; fa.be1 = be1; fa.g2 = g2; fa.be2 = be2;
    fa.ei = ei; fa.posIn = posIn; fa.b3 = b3;
    fa.out = out;
    fa.flags = flags; fa.gen = gen;
    k_fused<<<NBLK, 128, 0, stream>>>(fa);
}

// Round 6
// 198.862 us; speedup vs baseline: 8.4626x; 1.0503x over previous
//
#include <hip/hip_runtime.h>
#include <math.h>

// Problem constants (from reference setup_inputs)
#define BB 128        // batch
#define NN 2000       // nodes
#define EE 20000      // edges
#define CC 16         // channels
#define FUNC_LO 200   // func nodes: [200, 1800)
#define FUNC_HI 1800
#define OUT_LO 1800   // output nodes: [1800, 2000)
#define NFUNC 1600
#define NBLK 1600     // fused-kernel grid (1 block per func node)
#define EPSV 1e-5f
#define SS 40         // fixed slots per func node per direction (Poisson(10) tail safe)
#define NSLOT (NFUNC * SS)   // compact slot space: func nodes only
#define HP 129        // padded LDS stride

#define SCOPE_AGENT __HIP_MEMORY_SCOPE_AGENT

// ---- xe coherence scheme (rounds 4-5 validated) ----
// STORES: relaxed agent-scope atomics -> write-through past local L2 to the
//   coherence point; no fence instructions (fences cost 450us/barrier, round 3).
// LOADS:  plain cached loads; safe because xe is triple-buffered so every line
//   is first-touch within the dispatch (L2 fill comes from IC = fresh).
static __device__ __forceinline__ void xe_st(float* p, float v) {
    __hip_atomic_store(p, v, __ATOMIC_RELAXED, SCOPE_AGENT);
}

// ---------------- dataflow sync (round-6: replaces the grid barrier) ----------------
// Round-5 post-mortem: ~33us/gsync, dominated by 1599 waves polling ONE gen line
// (same-line IC bank serializes; ~20us backlog per poll round). A grid barrier is
// semantically overkill: each block's layer-L Phase A needs only its ~dIn producer
// blocks at layer L. Dataflow: progress[1600] flags (distinct words), consumer
// polls its producer list (<=40 scattered words). No centralized line anywhere;
// skew is absorbed by the DAG instead of amplified at global convergence points.
// Deadlock-free: flags are layer-monotonic, a block waits only on flags >= L and
// every block reaches L unconditionally once its producers do (base case: L0
// reads only xT -> no wait). Bounded spins -> no hang even if assumptions break.
// Co-residency (1600 blocks <= 2048 capacity) verified rounds 2-5, and is no
// longer even required for correctness (non-resident producers just run later).
__device__ __forceinline__ void arrive(int* progress, int L) {
    asm volatile("s_waitcnt vmcnt(0)" ::: "memory");  // this wave's xe stores at IC
    __syncthreads();                                  // all waves drained
    if (threadIdx.x == 0)
        __hip_atomic_store(&progress[blockIdx.x], L, __ATOMIC_RELAXED, SCOPE_AGENT);
}

__device__ __forceinline__ void wait_producers(const int* progress,
                                               const int* __restrict__ pblk,
                                               int cbase, int dIn, int L) {
    if (threadIdx.x < 64) {                 // wave 0 polls; lane j watches slot j
        int j = threadIdx.x;
        int pb = (j < dIn) ? pblk[cbase + j] : -1;   // dIn <= SS=40 < 64
        bool done = (pb < 0);
        int tries = 0;
        while (true) {
            if (!done)
                done = (__hip_atomic_load(&progress[pb], __ATOMIC_RELAXED,
                                          SCOPE_AGENT) >= L);
            if (__ballot(!done) == 0ull) break;
            __builtin_amdgcn_s_sleep(8);             // ~0.2us poll, scattered words
            if (++tries > (1 << 17)) break;          // safety valve vs deadlock
        }
    }
    __syncthreads();                        // release wave 1
}

// ---------------- prep: slot assign + operand gather + transpose + out zero ------
// Compact slot space (func nodes only). In-slot for func-dst edge e at dst d:
// pi = (d-FUNC_LO)*SS + rank. prodBlk[pi] = block that writes this row each layer:
// func-src -> that node's block; non-func-src -> the fill block (e % NBLK).
// Out-slots at func src, pre-compacted: func-dst edges from the front (wout = dst
// in-slot row); out-dst edges from the back (wout = dst node id).
__global__ void k_prep(const float* __restrict__ x, const int* __restrict__ ei,
                       const float* __restrict__ w1, const float* __restrict__ w3,
                       const float* __restrict__ b3,
                       int* __restrict__ degIn, int* __restrict__ degF,
                       int* __restrict__ degO, int* __restrict__ posIn,
                       float* __restrict__ xT, float* __restrict__ w1s,
                       float* __restrict__ w3s, float* __restrict__ b3s,
                       int* __restrict__ inoff, int* __restrict__ wout,
                       int* __restrict__ prodBlk, float* __restrict__ out)
{
    int t = blockIdx.x * 256 + threadIdx.x;
    if (t < EE) {
        int s = ei[t], d = ei[EE + t];
        bool dFn = (d >= FUNC_LO && d < FUNC_HI);
        bool sFn = (s >= FUNC_LO && s < FUNC_HI);
        int pi = -1;
        if (dFn) {                                  // in-slot at dst (compact)
            int p = atomicAdd(&degIn[d], 1);
            pi = (d - FUNC_LO) * SS + p;
            posIn[t] = pi;
            const float4* w1v = (const float4*)w1 + (size_t)t * 4;
            float4* w1o = (float4*)w1s + (size_t)pi * 4;
            #pragma unroll
            for (int i = 0; i < 4; i++) w1o[i] = w1v[i];
            inoff[pi] = s * BB;                     // layer-0 input row = xT[src]
            prodBlk[pi] = sFn ? (s - FUNC_LO) : (t % NBLK);  // row producer block
        }
        if (sFn) {                                  // out-slot at src (live only)
            int po = -1;
            if (dFn) {
                int q = atomicAdd(&degF[s], 1);
                po = (s - FUNC_LO) * SS + q;        // front: func-dst
                wout[po] = pi * BB;                 // write row = dst's in-slot
            } else if (d >= OUT_LO) {
                int q = atomicAdd(&degO[s], 1);
                po = (s - FUNC_LO) * SS + (SS - 1 - q);  // back: out-dst
                wout[po] = d;                       // dst node id (direct out add)
            }
            if (po >= 0) {
                const float4* w3v = (const float4*)w3 + (size_t)t * 4;
                float4* w3o = (float4*)w3s + (size_t)po * 4;
                #pragma unroll
                for (int i = 0; i < 4; i++) w3o[i] = w3v[i];
                b3s[po] = b3[t];
            }
        }
    }
    if (t < NN * BB) {
        out[t] = 0.0f;                 // zero output (no atomics to out here: safe)
        int n = t >> 7, b = t & (BB - 1);
        xT[t] = x[b * NN + n];         // coalesced write; scattered read (x = 1MB,
    }                                  // L2/L3-resident)
}

// ---------------- batchnorm + elu over a per-thread register column ----------------
__device__ __forceinline__ void bn_elu(float (&t)[CC],
                                       const float* __restrict__ g,
                                       const float* __restrict__ be,
                                       float* tile, float* part_s, float* part_ss,
                                       float* sc, float* sh, int b) {
    #pragma unroll
    for (int c = 0; c < CC; c++) tile[c * HP + b] = t[c];
    __syncthreads();
    {
        int c = b & 15, grp = b >> 4;          // 16 channels x 8 groups of 16 b
        float s = 0.f, ss = 0.f;
        #pragma unroll
        for (int i = 0; i < 16; i++) {
            float v = tile[c * HP + grp * 16 + i];
            s += v; ss += v * v;
        }
        part_s[grp * 16 + c] = s;
        part_ss[grp * 16 + c] = ss;
    }
    __syncthreads();
    if (b < CC) {
        float S = 0.f, SSm = 0.f;
        #pragma unroll
        for (int g8 = 0; g8 < 8; g8++) { S += part_s[g8 * 16 + b]; SSm += part_ss[g8 * 16 + b]; }
        float mean = S * (1.0f / BB);
        float var = SSm * (1.0f / BB) - mean * mean;
        float scale = rsqrtf(var + EPSV) * g[b];
        sc[b] = scale;
        sh[b] = be[b] - mean * scale;
    }
    __syncthreads();
    #pragma unroll
    for (int c = 0; c < CC; c++) {
        float u = t[c] * sc[c] + sh[c];
        t[c] = (u > 0.0f) ? u : (__expf(u) - 1.0f);
    }
}

// ---------------- fused kernel: fill + 4 layers (dataflow-synced) ----------------
struct FusedArgs {
    const float* xT; float* xeA; float* xeB; float* xeC;
    const float* w1s; const float* w2; const float* w3s; const float* b3s;
    const int* inoff; const int* wout; const int* prodBlk;
    const int* degIn; const int* degF; const int* degO;
    const float* g1; const float* be1; const float* g2; const float* be2;
    const int* ei; const int* posIn; const float* b3;
    float* out;
    int* progress;
};

template<bool FIRST, bool LAST>
__device__ __forceinline__ void layer_body(const FusedArgs& A,
    const float* __restrict__ xe_in, float* __restrict__ xe_out,
    int n, int cbase, int b, int dIn, int dF, int dO, float x0r,
    float* tile, float* part_s, float* part_ss, float* sc, float* sh)
{
    // ---- Phase A: acc[c] = sum_k xe_in[row(k)+b] * w1s[slot k][c] ----
    float a[CC];
    #pragma unroll
    for (int c = 0; c < CC; c++) a[c] = 0.0f;

    for (int k0 = 0; k0 < dIn; k0 += 16) {
        float v[16];
        #pragma unroll
        for (int j = 0; j < 16; j++) {       // 16 independent loads in flight
            v[j] = 0.0f;
            if (k0 + j < dIn) {              // uniform predicate
                int ro = FIRST ? A.inoff[cbase + k0 + j] : (cbase + k0 + j) * BB;
                v[j] = xe_in[ro + b];        // coalesced 512B row
            }
        }
        #pragma unroll
        for (int j = 0; j < 16; j++) {
            if (k0 + j < dIn) {
                const float* wr = &A.w1s[(size_t)(cbase + k0 + j) * CC]; // uniform -> s_load
                #pragma unroll
                for (int c = 0; c < CC; c++) a[c] += v[j] * wr[c];
            }
        }
    }

    bn_elu(a, A.g1 + n * CC, A.be1 + n * CC, tile, part_s, part_ss, sc, sh, b);

    // ---- 16x16 matmul from registers, wave-uniform weights ----
    float h2[CC];
    #pragma unroll
    for (int d = 0; d < CC; d++) h2[d] = 0.0f;
    const float* w2n = A.w2 + (size_t)n * (CC * CC);
    #pragma unroll
    for (int c = 0; c < CC; c++) {
        float av = a[c];
        #pragma unroll
        for (int d = 0; d < CC; d++) h2[d] += av * w2n[c * CC + d];
    }

    bn_elu(h2, A.g2 + n * CC, A.be2 + n * CC, tile, part_s, part_ss, sc, sh, b);

    // ---- Phase C: push to pre-compacted live out-slots (IC write-through) ----
    if (!LAST) {
        for (int q0 = 0; q0 < dF; q0 += 4) {
            #pragma unroll
            for (int j = 0; j < 4; j++) {
                int q = q0 + j;
                if (q >= dF) break;          // uniform
                int sl = cbase + q;
                const float* wr = &A.w3s[(size_t)sl * CC];   // uniform -> s_load
                float val = A.b3s[sl] + x0r;
                #pragma unroll
                for (int d = 0; d < CC; d++) val += h2[d] * wr[d];
                xe_st(&xe_out[A.wout[sl] + b], val);
            }
        }
    } else {
        for (int q0 = 0; q0 < dO; q0 += 4) {
            #pragma unroll
            for (int j = 0; j < 4; j++) {
                int q = q0 + j;
                if (q >= dO) break;          // uniform
                int sl = cbase + SS - 1 - q;
                const float* wr = &A.w3s[(size_t)sl * CC];
                float val = A.b3s[sl] + x0r;
                #pragma unroll
                for (int d = 0; d < CC; d++) val += h2[d] * wr[d];
                int dn = A.wout[sl];         // dst node id
                atomicAdd(&A.out[(size_t)b * NN + dn], val);   // scattered, fire&forget
            }
        }
    }
}

__global__ __launch_bounds__(128, 4) void k_fused(FusedArgs A)
{
    const int b = threadIdx.x;
    const int n = FUNC_LO + blockIdx.x;     // func nodes only
    const int cbase = blockIdx.x * SS;      // compact slot base

    __shared__ float tile[CC * HP];          // 8.25 KB
    __shared__ float part_s[128], part_ss[128];
    __shared__ float sc[CC], sh[CC];

    const int dIn = A.degIn[n];              // loaded ONCE for all 4 layers
    const int dF  = A.degF[n];
    const int dO  = A.degO[n];
    const float x0r = A.xT[n * BB + b];

    // ---- fill: constant rows for non-func-src edges (same value every layer) ----
    // These rows' consumers wait on progress[e % NBLK] >= L (L>=1), and this block
    // sets progress=1 only AFTER its fill loop -> fill visibility is guaranteed.
    for (int e = blockIdx.x; e < EE; e += NBLK) {
        int s = A.ei[e];
        if (s >= FUNC_LO && s < FUNC_HI) continue;   // func src -> layer_body writes it
        int d = A.ei[EE + e];
        float val = A.b3[e] + A.xT[s * BB + b];
        if (d >= FUNC_LO && d < FUNC_HI) {
            int ro = A.posIn[e] * BB;
            xe_st(&A.xeA[ro + b], val);
            xe_st(&A.xeB[ro + b], val);
            xe_st(&A.xeC[ro + b], val);
        } else if (d >= OUT_LO) {
            atomicAdd(&A.out[(size_t)b * NN + d], val);
        }
    }

    // ---- 4 layers, producer-list dataflow sync (no global barrier) ----
    layer_body<true,  false>(A, A.xT,  A.xeA, n, cbase, b, dIn, dF, dO, x0r,
                             tile, part_s, part_ss, sc, sh);
    arrive(A.progress, 1);
    wait_producers(A.progress, A.prodBlk, cbase, dIn, 1);
    layer_body<false, false>(A, A.xeA, A.xeB, n, cbase, b, dIn, dF, dO, x0r,
                             tile, part_s, part_ss, sc, sh);
    arrive(A.progress, 2);
    wait_producers(A.progress, A.prodBlk, cbase, dIn, 2);
    layer_body<false, false>(A, A.xeB, A.xeC, n, cbase, b, dIn, dF, dO, x0r,
                             tile, part_s, part_ss, sc, sh);
    arrive(A.progress, 3);
    wait_producers(A.progress, A.prodBlk, cbase, dIn, 3);
    layer_body<false, true >(A, A.xeC, nullptr, n, cbase, b, dIn, dF, dO, x0r,
                             tile, part_s, part_ss, sc, sh);
    // last layer atomic-adds straight into out; kernel end publishes everything
}

extern "C" void kernel_launch(void* const* d_in, const int* in_sizes, int n_in,
                              void* d_out, int out_size, void* d_ws, size_t ws_size,
                              hipStream_t stream) {
    const float* x   = (const float*)d_in[0];
    const float* w1  = (const float*)d_in[1];
    // d_in[2] = b1: cancels through batchnorm
    const float* w2  = (const float*)d_in[3];
    // d_in[4] = b2: cancels through batchnorm
    const float* w3  = (const float*)d_in[5];
    const float* b3  = (const float*)d_in[6];
    const float* g1  = (const float*)d_in[7];
    const float* be1 = (const float*)d_in[8];
    const float* g2  = (const float*)d_in[9];
    const float* be2 = (const float*)d_in[10];
    const int* ei    = (const int*)d_in[11];
    float* out = (float*)d_out;

    // workspace partition (compact slot layout: NSLOT = 1600*40 = 64000 rows)
    char* ws = (char*)d_ws;
    float* xT   = (float*)ws;  ws += (size_t)NN * BB * 4;            // 1.0 MB
    float* xeA  = (float*)ws;  ws += (size_t)NSLOT * BB * 4;         // 32.8 MB
    float* xeB  = (float*)ws;  ws += (size_t)NSLOT * BB * 4;         // 32.8 MB
    float* xeC  = (float*)ws;  ws += (size_t)NSLOT * BB * 4;         // 32.8 MB
    float* w1s  = (float*)ws;  ws += (size_t)NSLOT * CC * 4;         // 4.1 MB
    float* w3s  = (float*)ws;  ws += (size_t)NSLOT * CC * 4;         // 4.1 MB
    float* b3s  = (float*)ws;  ws += (size_t)NSLOT * 4;
    int* degIn  = (int*)ws;    ws += (size_t)NN * 4;                 // contiguous meta:
    int* degF   = (int*)ws;    ws += (size_t)NN * 4;                 //   degIn,degF,degO,
    int* degO   = (int*)ws;    ws += (size_t)NN * 4;                 //   progress zeroed
    int* progress = (int*)ws;  ws += (size_t)NBLK * 4;               //   by ONE memset
    int* posIn  = (int*)ws;    ws += (size_t)EE * 4;
    int* inoff  = (int*)ws;    ws += (size_t)NSLOT * 4;
    int* wout   = (int*)ws;    ws += (size_t)NSLOT * 4;
    int* prodBlk= (int*)ws;    ws += (size_t)NSLOT * 4;

    hipMemsetAsync(degIn, 0, (3 * NN + NBLK) * sizeof(int), stream);
    k_prep<<<(NN * BB + 255) / 256, 256, 0, stream>>>(
        x, ei, w1, w3, b3, degIn, degF, degO, posIn,
        xT, w1s, w3s, b3s, inoff, wout, prodBlk, out);

    FusedArgs fa;
    fa.xT = xT; fa.xeA = xeA; fa.xeB = xeB; fa.xeC = xeC;
    fa.w1s = w1s; fa.w2 = w2; fa.w3s = w3s; fa.b3s = b3s;
    fa.inoff = inoff; fa.wout = wout; fa.prodBlk = prodBlk;
    fa.degIn = degIn; fa.degF = degF; fa.degO = degO;
    fa.g1 = g1; fa.be1 = be1; fa.g2 = g2; fa.be2 = be2;
    fa.ei = ei; fa.posIn = posIn; fa.b3 = b3;
    fa.out = out;
    fa.progress = progress;
    k_fused<<<NBLK, 128, 0, stream>>>(fa);
}

// Round 7
// 165.772 us; speedup vs baseline: 10.1519x; 1.1996x over previous
//
#include <hip/hip_runtime.h>
#include <math.h>

// Problem constants (from reference setup_inputs)
#define BB 128        // batch
#define NN 2000       // nodes
#define EE 20000      // edges
#define CC 16         // channels
#define FUNC_LO 200   // func nodes: [200, 1800)
#define FUNC_HI 1800
#define OUT_LO 1800   // output nodes: [1800, 2000)
#define NFUNC 1600
#define NBLK 1600     // fused-kernel grid (1 block per func node)
#define EPSV 1e-5f
#define SS 40         // fixed slots per func node per direction (Poisson(10) tail safe)
#define NSLOT (NFUNC * SS)   // compact slot space: func nodes only
#define HP 129        // padded LDS stride

#define SCOPE_AGENT __HIP_MEMORY_SCOPE_AGENT

// ---- xe coherence scheme (rounds 4-6 validated) ----
// STORES: relaxed agent-scope atomics -> write-through past local L2 to the
//   coherence point; no fence instructions (fences cost 450us/barrier, round 3).
// LOADS:  plain cached loads; safe because xe is triple-buffered so every line
//   is first-touch within the dispatch (L2 fill comes from IC = fresh).
static __device__ __forceinline__ void xe_st(float* p, float v) {
    __hip_atomic_store(p, v, __ATOMIC_RELAXED, SCOPE_AGENT);
}

// ---------------- dataflow sync (round-6 validated) ----------------
// progress[1600] per-block layer flags (distinct words); consumer polls only its
// ~dIn producer blocks (scattered words, no hot line). Deadlock-free (monotonic
// flags, acyclic layer DAG); bounded spins -> no hang. Requires co-residency:
// 1600 blocks <= capacity (LDS 15.7KB -> 10 blocks/CU; verified occupancy r2-r6).
__device__ __forceinline__ void arrive(int* progress, int L) {
    asm volatile("s_waitcnt vmcnt(0)" ::: "memory");  // this wave's xe stores at IC
    __syncthreads();                                  // all waves drained
    if (threadIdx.x == 0)
        __hip_atomic_store(&progress[blockIdx.x], L, __ATOMIC_RELAXED, SCOPE_AGENT);
}

__device__ __forceinline__ void wait_producers(const int* progress,
                                               const int* __restrict__ pblk,
                                               int cbase, int dIn, int L) {
    if (threadIdx.x < 64) {                 // wave 0 polls; lane j watches slot j
        int j = threadIdx.x;
        int pb = (j < dIn) ? pblk[cbase + j] : -1;   // dIn <= SS=40 < 64
        bool done = (pb < 0);
        int tries = 0;
        while (true) {
            if (!done)
                done = (__hip_atomic_load(&progress[pb], __ATOMIC_RELAXED,
                                          SCOPE_AGENT) >= L);
            if (__ballot(!done) == 0ull) break;
            __builtin_amdgcn_s_sleep(8);             // ~0.2us poll, scattered words
            if (++tries > (1 << 17)) break;          // safety valve vs deadlock
        }
    }
    __syncthreads();                        // release wave 1
}

// ---------------- prep: slot assign + operand gather + transpose + out zero ------
// Compact slot space (func nodes only). In-slot for func-dst edge e at dst d:
// pi = (d-FUNC_LO)*SS + rank. prodBlk[pi] = block that writes this row each layer:
// func-src -> that node's block; non-func-src -> the fill block (e % NBLK).
// Out-slots at func src, pre-compacted: func-dst edges from the front (wout = dst
// in-slot row); out-dst edges from the back (wout = dst node id).
__global__ void k_prep(const float* __restrict__ x, const int* __restrict__ ei,
                       const float* __restrict__ w1, const float* __restrict__ w3,
                       const float* __restrict__ b3,
                       int* __restrict__ degIn, int* __restrict__ degF,
                       int* __restrict__ degO, int* __restrict__ posIn,
                       float* __restrict__ xT, float* __restrict__ w1s,
                       float* __restrict__ w3s, float* __restrict__ b3s,
                       int* __restrict__ inoff, int* __restrict__ wout,
                       int* __restrict__ prodBlk, float* __restrict__ out)
{
    int t = blockIdx.x * 256 + threadIdx.x;
    if (t < EE) {
        int s = ei[t], d = ei[EE + t];
        bool dFn = (d >= FUNC_LO && d < FUNC_HI);
        bool sFn = (s >= FUNC_LO && s < FUNC_HI);
        int pi = -1;
        if (dFn) {                                  // in-slot at dst (compact)
            int p = atomicAdd(&degIn[d], 1);
            pi = (d - FUNC_LO) * SS + p;
            posIn[t] = pi;
            const float4* w1v = (const float4*)w1 + (size_t)t * 4;
            float4* w1o = (float4*)w1s + (size_t)pi * 4;
            #pragma unroll
            for (int i = 0; i < 4; i++) w1o[i] = w1v[i];
            inoff[pi] = s * BB;                     // layer-0 input row = xT[src]
            prodBlk[pi] = sFn ? (s - FUNC_LO) : (t % NBLK);  // row producer block
        }
        if (sFn) {                                  // out-slot at src (live only)
            int po = -1;
            if (dFn) {
                int q = atomicAdd(&degF[s], 1);
                po = (s - FUNC_LO) * SS + q;        // front: func-dst
                wout[po] = pi * BB;                 // write row = dst's in-slot
            } else if (d >= OUT_LO) {
                int q = atomicAdd(&degO[s], 1);
                po = (s - FUNC_LO) * SS + (SS - 1 - q);  // back: out-dst
                wout[po] = d;                       // dst node id (direct out add)
            }
            if (po >= 0) {
                const float4* w3v = (const float4*)w3 + (size_t)t * 4;
                float4* w3o = (float4*)w3s + (size_t)po * 4;
                #pragma unroll
                for (int i = 0; i < 4; i++) w3o[i] = w3v[i];
                b3s[po] = b3[t];
            }
        }
    }
    if (t < NN * BB) {
        out[t] = 0.0f;                 // zero output (no atomics to out here: safe)
        int n = t >> 7, b = t & (BB - 1);
        xT[t] = x[b * NN + n];         // coalesced write; scattered read (x = 1MB,
    }                                  // L2/L3-resident)
}

// ---------------- batchnorm + elu over a per-thread register column ----------------
__device__ __forceinline__ void bn_elu(float (&t)[CC],
                                       const float* __restrict__ g,
                                       const float* __restrict__ be,
                                       float* tile, float* part_s, float* part_ss,
                                       float* sc, float* sh, int b) {
    #pragma unroll
    for (int c = 0; c < CC; c++) tile[c * HP + b] = t[c];
    __syncthreads();
    {
        int c = b & 15, grp = b >> 4;          // 16 channels x 8 groups of 16 b
        float s = 0.f, ss = 0.f;
        #pragma unroll
        for (int i = 0; i < 16; i++) {
            float v = tile[c * HP + grp * 16 + i];
            s += v; ss += v * v;
        }
        part_s[grp * 16 + c] = s;
        part_ss[grp * 16 + c] = ss;
    }
    __syncthreads();
    if (b < CC) {
        float S = 0.f, SSm = 0.f;
        #pragma unroll
        for (int g8 = 0; g8 < 8; g8++) { S += part_s[g8 * 16 + b]; SSm += part_ss[g8 * 16 + b]; }
        float mean = S * (1.0f / BB);
        float var = SSm * (1.0f / BB) - mean * mean;
        float scale = rsqrtf(var + EPSV) * g[b];
        sc[b] = scale;
        sh[b] = be[b] - mean * scale;
    }
    __syncthreads();
    #pragma unroll
    for (int c = 0; c < CC; c++) {
        float u = t[c] * sc[c] + sh[c];
        t[c] = (u > 0.0f) ? u : (__expf(u) - 1.0f);
    }
}

// ---------------- fused kernel: fill + 4 layers (dataflow-synced) ----------------
struct FusedArgs {
    const float* xT; float* xeA; float* xeB; float* xeC;
    const float* w1s; const float* w2; const float* w3s; const float* b3s;
    const int* inoff; const int* wout; const int* prodBlk;
    const int* degIn; const int* degF; const int* degO;
    const float* g1; const float* be1; const float* g2; const float* be2;
    const int* ei; const int* posIn; const float* b3;
    float* out;
    int* progress;
};

// Round-7: all per-node constants (w1,w3,w2,b3,wout,inoff) come from LDS, staged
// ONCE before layer 0. Round-6 post-mortem: these are wave-uniform -> compiler
// used s_load; SMEM returns out-of-order so every consumption group needs a full
// lgkmcnt(0) drain (~300cy K$-miss round trip, K$ thrashed by 6 blocks/CU x 6KB)
// -> ~10-20us/layer of scalar-stall with VALU idle (VALUBusy 14%). LDS reads are
// broadcast (conflict-free), return IN-ORDER (pipelined lgkmcnt(N)), loaded once.
template<bool FIRST, bool LAST>
__device__ __forceinline__ void layer_body(const FusedArgs& A,
    const float* __restrict__ xe_in, float* __restrict__ xe_out,
    int n, int b, int dIn, int dF, int dO, float x0r,
    const float* w1L, const float* w3L, const float* w2L, const float* b3L,
    const int* ioL, const int* woL,
    float* tile, float* part_s, float* part_ss, float* sc, float* sh)
{
    // ---- Phase A: acc[c] = sum_k xe_in[row(k)+b] * w1L[k][c] ----
    float a[CC];
    #pragma unroll
    for (int c = 0; c < CC; c++) a[c] = 0.0f;

    for (int k0 = 0; k0 < dIn; k0 += 16) {
        float v[16];
        #pragma unroll
        for (int j = 0; j < 16; j++) {       // 16 independent global loads in flight
            v[j] = 0.0f;
            if (k0 + j < dIn) {              // uniform predicate
                int ro = FIRST ? ioL[k0 + j] : (k0 + j) * BB;
                v[j] = xe_in[ro + b];        // coalesced 512B row
            }
        }
        #pragma unroll
        for (int j = 0; j < 16; j++) {
            if (k0 + j < dIn) {
                const float* wr = &w1L[(k0 + j) * CC];   // LDS broadcast, pipelined
                #pragma unroll
                for (int c = 0; c < CC; c++) a[c] += v[j] * wr[c];
            }
        }
    }

    bn_elu(a, A.g1 + n * CC, A.be1 + n * CC, tile, part_s, part_ss, sc, sh, b);

    // ---- 16x16 matmul from registers, LDS-broadcast weights ----
    float h2[CC];
    #pragma unroll
    for (int d = 0; d < CC; d++) h2[d] = 0.0f;
    #pragma unroll
    for (int c = 0; c < CC; c++) {
        float av = a[c];
        #pragma unroll
        for (int d = 0; d < CC; d++) h2[d] += av * w2L[c * CC + d];
    }

    bn_elu(h2, A.g2 + n * CC, A.be2 + n * CC, tile, part_s, part_ss, sc, sh, b);

    // ---- Phase C: push to pre-compacted live out-slots (IC write-through) ----
    if (!LAST) {
        for (int q0 = 0; q0 < dF; q0 += 4) {
            #pragma unroll
            for (int j = 0; j < 4; j++) {
                int q = q0 + j;
                if (q >= dF) break;          // uniform
                const float* wr = &w3L[q * CC];          // LDS broadcast
                float val = b3L[q] + x0r;
                #pragma unroll
                for (int d = 0; d < CC; d++) val += h2[d] * wr[d];
                xe_st(&xe_out[woL[q] + b], val);
            }
        }
    } else {
        for (int q0 = 0; q0 < dO; q0 += 4) {
            #pragma unroll
            for (int j = 0; j < 4; j++) {
                int q = q0 + j;
                if (q >= dO) break;          // uniform
                int ql = SS - 1 - q;
                const float* wr = &w3L[ql * CC];
                float val = b3L[ql] + x0r;
                #pragma unroll
                for (int d = 0; d < CC; d++) val += h2[d] * wr[d];
                int dn = woL[ql];            // dst node id
                atomicAdd(&A.out[(size_t)b * NN + dn], val);   // scattered, fire&forget
            }
        }
    }
}

__global__ __launch_bounds__(128, 4) void k_fused(FusedArgs A)
{
    const int b = threadIdx.x;
    const int blk = blockIdx.x;
    const int n = FUNC_LO + blk;            // func nodes only
    const int cbase = blk * SS;             // compact slot base

    __shared__ float tile[CC * HP];          // 8.25 KB
    __shared__ float part_s[128], part_ss[128];
    __shared__ float sc[CC], sh[CC];
    __shared__ float w1L[SS * CC];           // 2.5 KB  per-node weights, staged once
    __shared__ float w3L[SS * CC];           // 2.5 KB
    __shared__ float w2L[CC * CC];           // 1.0 KB
    __shared__ float b3L[SS];
    __shared__ int   ioL[SS];                // layer-0 input row offsets
    __shared__ int   woL[SS];                // out-slot write targets
    // total ~15.7 KB -> 10 blocks/CU capacity >= 6.25 needed (co-residency safe)

    // ---- stage per-node constants into LDS (once, coalesced vector loads) ----
    #pragma unroll
    for (int i = b; i < SS * CC; i += 128) {         // 5 iters each
        w1L[i] = A.w1s[(size_t)cbase * CC + i];
        w3L[i] = A.w3s[(size_t)cbase * CC + i];
    }
    #pragma unroll
    for (int i = b; i < CC * CC; i += 128)           // 2 iters
        w2L[i] = A.w2[(size_t)n * CC * CC + i];
    if (b < SS) {
        b3L[b] = A.b3s[cbase + b];
        ioL[b] = A.inoff[cbase + b];
        woL[b] = A.wout[cbase + b];
    }
    const int dIn = A.degIn[n];              // loaded ONCE for all 4 layers
    const int dF  = A.degF[n];
    const int dO  = A.degO[n];
    const float x0r = A.xT[n * BB + b];

    // ---- fill: constant rows for non-func-src edges (same value every layer) ----
    // Consumers wait on progress[e % NBLK] >= L (L>=1); this block sets progress=1
    // only AFTER its fill loop -> fill visibility guaranteed. (No LDS use here.)
    for (int e = blk; e < EE; e += NBLK) {
        int s = A.ei[e];
        if (s >= FUNC_LO && s < FUNC_HI) continue;   // func src -> layer_body writes it
        int d = A.ei[EE + e];
        float val = A.b3[e] + A.xT[s * BB + b];
        if (d >= FUNC_LO && d < FUNC_HI) {
            int ro = A.posIn[e] * BB;
            xe_st(&A.xeA[ro + b], val);
            xe_st(&A.xeB[ro + b], val);
            xe_st(&A.xeC[ro + b], val);
        } else if (d >= OUT_LO) {
            atomicAdd(&A.out[(size_t)b * NN + d], val);
        }
    }
    __syncthreads();                         // LDS staging visible to all waves

    // xe_in base for non-first layers is this block's compact row region
    const float* xeAr = A.xeA + (size_t)cbase * BB;
    const float* xeBr = A.xeB + (size_t)cbase * BB;
    const float* xeCr = A.xeC + (size_t)cbase * BB;

    // ---- 4 layers, producer-list dataflow sync (no global barrier) ----
    layer_body<true,  false>(A, A.xT, A.xeA, n, b, dIn, dF, dO, x0r,
                             w1L, w3L, w2L, b3L, ioL, woL,
                             tile, part_s, part_ss, sc, sh);
    arrive(A.progress, 1);
    wait_producers(A.progress, A.prodBlk, cbase, dIn, 1);
    layer_body<false, false>(A, xeAr, A.xeB, n, b, dIn, dF, dO, x0r,
                             w1L, w3L, w2L, b3L, ioL, woL,
                             tile, part_s, part_ss, sc, sh);
    arrive(A.progress, 2);
    wait_producers(A.progress, A.prodBlk, cbase, dIn, 2);
    layer_body<false, false>(A, xeBr, A.xeC, n, b, dIn, dF, dO, x0r,
                             w1L, w3L, w2L, b3L, ioL, woL,
                             tile, part_s, part_ss, sc, sh);
    arrive(A.progress, 3);
    wait_producers(A.progress, A.prodBlk, cbase, dIn, 3);
    layer_body<false, true >(A, xeCr, nullptr, n, b, dIn, dF, dO, x0r,
                             w1L, w3L, w2L, b3L, ioL, woL,
                             tile, part_s, part_ss, sc, sh);
    // last layer atomic-adds straight into out; kernel end publishes everything
}

extern "C" void kernel_launch(void* const* d_in, const int* in_sizes, int n_in,
                              void* d_out, int out_size, void* d_ws, size_t ws_size,
                              hipStream_t stream) {
    const float* x   = (const float*)d_in[0];
    const float* w1  = (const float*)d_in[1];
    // d_in[2] = b1: cancels through batchnorm
    const float* w2  = (const float*)d_in[3];
    // d_in[4] = b2: cancels through batchnorm
    const float* w3  = (const float*)d_in[5];
    const float* b3  = (const float*)d_in[6];
    const float* g1  = (const float*)d_in[7];
    const float* be1 = (const float*)d_in[8];
    const float* g2  = (const float*)d_in[9];
    const float* be2 = (const float*)d_in[10];
    const int* ei    = (const int*)d_in[11];
    float* out = (float*)d_out;

    // workspace partition (compact slot layout: NSLOT = 1600*40 = 64000 rows)
    char* ws = (char*)d_ws;
    float* xT   = (float*)ws;  ws += (size_t)NN * BB * 4;            // 1.0 MB
    float* xeA  = (float*)ws;  ws += (size_t)NSLOT * BB * 4;         // 32.8 MB
    float* xeB  = (float*)ws;  ws += (size_t)NSLOT * BB * 4;         // 32.8 MB
    float* xeC  = (float*)ws;  ws += (size_t)NSLOT * BB * 4;         // 32.8 MB
    float* w1s  = (float*)ws;  ws += (size_t)NSLOT * CC * 4;         // 4.1 MB
    float* w3s  = (float*)ws;  ws += (size_t)NSLOT * CC * 4;         // 4.1 MB
    float* b3s  = (float*)ws;  ws += (size_t)NSLOT * 4;
    int* degIn  = (int*)ws;    ws += (size_t)NN * 4;                 // contiguous meta:
    int* degF   = (int*)ws;    ws += (size_t)NN * 4;                 //   degIn,degF,degO,
    int* degO   = (int*)ws;    ws += (size_t)NN * 4;                 //   progress zeroed
    int* progress = (int*)ws;  ws += (size_t)NBLK * 4;               //   by ONE memset
    int* posIn  = (int*)ws;    ws += (size_t)EE * 4;
    int* inoff  = (int*)ws;    ws += (size_t)NSLOT * 4;
    int* wout   = (int*)ws;    ws += (size_t)NSLOT * 4;
    int* prodBlk= (int*)ws;    ws += (size_t)NSLOT * 4;

    hipMemsetAsync(degIn, 0, (3 * NN + NBLK) * sizeof(int), stream);
    k_prep<<<(NN * BB + 255) / 256, 256, 0, stream>>>(
        x, ei, w1, w3, b3, degIn, degF, degO, posIn,
        xT, w1s, w3s, b3s, inoff, wout, prodBlk, out);

    FusedArgs fa;
    fa.xT = xT; fa.xeA = xeA; fa.xeB = xeB; fa.xeC = xeC;
    fa.w1s = w1s; fa.w2 = w2; fa.w3s = w3s; fa.b3s = b3s;
    fa.inoff = inoff; fa.wout = wout; fa.prodBlk = prodBlk;
    fa.degIn = degIn; fa.degF = degF; fa.degO = degO;
    fa.g1 = g1; fa.be1 = be1; fa.g2 = g2; fa.be2 = be2;
    fa.ei = ei; fa.posIn = posIn; fa.b3 = b3;
    fa.out = out;
    fa.progress = progress;
    k_fused<<<NBLK, 128, 0, stream>>>(fa);
}